// Round 1
// baseline (1991.220 us; speedup 1.0000x reference)
//
#include <hip/hip_runtime.h>
#include <math.h>

#define P 65536

// ---------------------------------------------------------------------------
// Fused conv1x1 (GEMM M=Cout, K=Cin, N=65536) with optional shift_plus on the
// input, BN epilogue, exact GELU, and residual add.
// Block: 256 threads, tile = 20 out-channels x 1024 pixels (4 pixels/thread).
// W tile staged in LDS [CIN][20]; inner loop reads are uniform -> broadcast.
// ---------------------------------------------------------------------------
template<int CIN, int SHIFT_IN, int BN, int GELU, int RESID>
__global__ __launch_bounds__(256) void convk(
    const float* __restrict__ X, const float* __restrict__ Wt,
    const float* __restrict__ Bi,
    const float* __restrict__ bg, const float* __restrict__ bb,
    const float* __restrict__ bm, const float* __restrict__ bv,
    const float* __restrict__ R, float* __restrict__ O)
{
    constexpr int TO = 20, PPT = 4, NT = 256;
    __shared__ float ws[CIN][TO];
    const int obase = blockIdx.y * TO;
    const int pbase = blockIdx.x * (NT * PPT);
    const int tid = threadIdx.x;

    for (int i = tid; i < CIN * TO; i += NT) {
        int o = i / CIN;
        int k = i - o * CIN;
        ws[k][o] = Wt[(size_t)(obase + o) * CIN + k];
    }
    __syncthreads();

    int pix[PPT];
    int src[5][PPT];
    #pragma unroll
    for (int j = 0; j < PPT; j++) {
        int pp = pbase + tid + j * NT;
        pix[j] = pp;
        if (SHIFT_IN) {
            int h = pp >> 8, w = pp & 255;
            src[0][j] = (w < 255) ? pp + 1   : -1;
            src[1][j] = (w > 0)   ? pp - 1   : -1;
            src[2][j] = (h < 255) ? pp + 256 : -1;
            src[3][j] = (h > 0)   ? pp - 256 : -1;
            src[4][j] = pp;
        }
    }

    float acc[PPT][TO];
    #pragma unroll
    for (int j = 0; j < PPT; j++)
        #pragma unroll
        for (int o = 0; o < TO; o++) acc[j][o] = 0.f;

    constexpr int GS = CIN / 5;
    #pragma unroll
    for (int g = 0; g < 5; ++g) {
        for (int k = g * GS; k < (g + 1) * GS; ++k) {
            const float* Xk = X + (size_t)k * P;
            float xv[PPT];
            #pragma unroll
            for (int j = 0; j < PPT; j++) {
                if (SHIFT_IN) {
                    int s = src[g][j];
                    xv[j] = (s >= 0) ? Xk[s] : 0.f;
                } else {
                    xv[j] = Xk[pix[j]];
                }
            }
            #pragma unroll
            for (int o4 = 0; o4 < TO / 4; o4++) {
                const float4 wv = *reinterpret_cast<const float4*>(&ws[k][o4 * 4]);
                #pragma unroll
                for (int j = 0; j < PPT; j++) {
                    acc[j][o4 * 4 + 0] = fmaf(xv[j], wv.x, acc[j][o4 * 4 + 0]);
                    acc[j][o4 * 4 + 1] = fmaf(xv[j], wv.y, acc[j][o4 * 4 + 1]);
                    acc[j][o4 * 4 + 2] = fmaf(xv[j], wv.z, acc[j][o4 * 4 + 2]);
                    acc[j][o4 * 4 + 3] = fmaf(xv[j], wv.w, acc[j][o4 * 4 + 3]);
                }
            }
        }
    }

    #pragma unroll
    for (int o = 0; o < TO; o++) {
        const int oc = obase + o;
        float sc = 1.f;
        float sh = Bi[oc];
        if (BN) {
            float inv = bg[oc] * rsqrtf(bv[oc] + 1e-5f);
            sh = bb[oc] + (sh - bm[oc]) * inv;
            sc = inv;
        }
        #pragma unroll
        for (int j = 0; j < PPT; j++) {
            float y = acc[j][o] * sc + sh;
            if (GELU) y = 0.5f * y * (1.f + erff(y * 0.70710678118654752f));
            if (RESID) y += R[(size_t)oc * P + pix[j]];
            O[(size_t)oc * P + pix[j]] = y;
        }
    }
}

// ---------------------------------------------------------------------------
// Window attention, 8x8 windows (slice 0 of qkv: q ch [0,90), v ch [90,180)).
// One wave per window (64 tokens), 4 windows per block. c=15 per head.
// Scores s_ij = q_i . q_j (note: q with itself), softmax, o = p @ v.
// Shift handled by gathering from (and writing back to) rolled-source pixel.
// ---------------------------------------------------------------------------
__global__ __launch_bounds__(256) void attn8k(const float* __restrict__ QKV,
                                              float* __restrict__ O, int sh)
{
    const int tid = threadIdx.x;
    const int wi = tid >> 6;
    const int lane = tid & 63;
    const int win = blockIdx.x * 4 + wi;
    const int hd = blockIdx.y;
    const int wy = win >> 5, wx = win & 31;
    const int ty = lane >> 3, tx = lane & 7;
    const int gh = (wy * 8 + ty - sh) & 255;
    const int gw = (wx * 8 + tx - sh) & 255;
    const int p = (gh << 8) | gw;

    __shared__ float q_s[4][64][16];
    __shared__ float v_s[4][64][16];

    const float* Q = QKV + (size_t)(hd * 15) * P + p;
    const float* V = QKV + (size_t)(90 + hd * 15) * P + p;
    #pragma unroll
    for (int c = 0; c < 15; c++) {
        q_s[wi][lane][c] = Q[(size_t)c * P];
        v_s[wi][lane][c] = V[(size_t)c * P];
    }
    q_s[wi][lane][15] = 0.f;
    v_s[wi][lane][15] = 0.f;
    __syncthreads();

    float qi[16];
    #pragma unroll
    for (int c = 0; c < 16; c++) qi[c] = q_s[wi][lane][c];

    float s[64];
    for (int j = 0; j < 64; j++) {
        const float4* qr = reinterpret_cast<const float4*>(q_s[wi][j]);
        float d = 0.f;
        #pragma unroll
        for (int c4 = 0; c4 < 4; c4++) {
            float4 a = qr[c4];
            d = fmaf(qi[c4 * 4 + 0], a.x, d);
            d = fmaf(qi[c4 * 4 + 1], a.y, d);
            d = fmaf(qi[c4 * 4 + 2], a.z, d);
            d = fmaf(qi[c4 * 4 + 3], a.w, d);
        }
        s[j] = d;
    }
    float mx = s[0];
    for (int j = 1; j < 64; j++) mx = fmaxf(mx, s[j]);
    float l = 0.f;
    for (int j = 0; j < 64; j++) { s[j] = __expf(s[j] - mx); l += s[j]; }

    float o[16];
    #pragma unroll
    for (int c = 0; c < 16; c++) o[c] = 0.f;
    for (int j = 0; j < 64; j++) {
        const float4* vr = reinterpret_cast<const float4*>(v_s[wi][j]);
        #pragma unroll
        for (int c4 = 0; c4 < 4; c4++) {
            float4 a = vr[c4];
            o[c4 * 4 + 0] = fmaf(s[j], a.x, o[c4 * 4 + 0]);
            o[c4 * 4 + 1] = fmaf(s[j], a.y, o[c4 * 4 + 1]);
            o[c4 * 4 + 2] = fmaf(s[j], a.z, o[c4 * 4 + 2]);
            o[c4 * 4 + 3] = fmaf(s[j], a.w, o[c4 * 4 + 3]);
        }
    }
    float rl = 1.f / l;
    #pragma unroll
    for (int c = 0; c < 15; c++)
        O[(size_t)(hd * 15 + c) * P + p] = o[c] * rl;
}

// ---------------------------------------------------------------------------
// Window attention, 16x16 windows (slice 1: q ch [180,270), v ch [270,360)).
// One 256-thread block per window; thread = token; online softmax, 64-chunks.
// Output channels [90,180) of the attention-out buffer.
// ---------------------------------------------------------------------------
__global__ __launch_bounds__(256) void attn16k(const float* __restrict__ QKV,
                                               float* __restrict__ O, int sh)
{
    const int tid = threadIdx.x;
    const int win = blockIdx.x;
    const int hd = blockIdx.y;
    const int wy = win >> 4, wx = win & 15;
    const int ty = tid >> 4, tx = tid & 15;
    const int gh = (wy * 16 + ty - sh) & 255;
    const int gw = (wx * 16 + tx - sh) & 255;
    const int p = (gh << 8) | gw;

    __shared__ float q_s[256][16];
    __shared__ float v_s[256][16];

    const float* Q = QKV + (size_t)(180 + hd * 15) * P + p;
    const float* V = QKV + (size_t)(270 + hd * 15) * P + p;
    #pragma unroll
    for (int c = 0; c < 15; c++) {
        q_s[tid][c] = Q[(size_t)c * P];
        v_s[tid][c] = V[(size_t)c * P];
    }
    q_s[tid][15] = 0.f;
    v_s[tid][15] = 0.f;
    __syncthreads();

    float qi[16];
    #pragma unroll
    for (int c = 0; c < 16; c++) qi[c] = q_s[tid][c];

    float m = -3.0e38f, l = 0.f;
    float o[16];
    #pragma unroll
    for (int c = 0; c < 16; c++) o[c] = 0.f;

    for (int jc = 0; jc < 4; jc++) {
        float s[64];
        float cm = -3.0e38f;
        for (int jj = 0; jj < 64; jj++) {
            const int j = jc * 64 + jj;
            const float4* qr = reinterpret_cast<const float4*>(q_s[j]);
            float d = 0.f;
            #pragma unroll
            for (int c4 = 0; c4 < 4; c4++) {
                float4 a = qr[c4];
                d = fmaf(qi[c4 * 4 + 0], a.x, d);
                d = fmaf(qi[c4 * 4 + 1], a.y, d);
                d = fmaf(qi[c4 * 4 + 2], a.z, d);
                d = fmaf(qi[c4 * 4 + 3], a.w, d);
            }
            s[jj] = d;
            cm = fmaxf(cm, d);
        }
        float nm = fmaxf(m, cm);
        float rs = __expf(m - nm);
        l *= rs;
        #pragma unroll
        for (int c = 0; c < 16; c++) o[c] *= rs;
        for (int jj = 0; jj < 64; jj++) {
            const int j = jc * 64 + jj;
            float e = __expf(s[jj] - nm);
            l += e;
            const float4* vr = reinterpret_cast<const float4*>(v_s[j]);
            #pragma unroll
            for (int c4 = 0; c4 < 4; c4++) {
                float4 a = vr[c4];
                o[c4 * 4 + 0] = fmaf(e, a.x, o[c4 * 4 + 0]);
                o[c4 * 4 + 1] = fmaf(e, a.y, o[c4 * 4 + 1]);
                o[c4 * 4 + 2] = fmaf(e, a.z, o[c4 * 4 + 2]);
                o[c4 * 4 + 3] = fmaf(e, a.w, o[c4 * 4 + 3]);
            }
        }
        m = nm;
    }
    float rl = 1.f / l;
    #pragma unroll
    for (int c = 0; c < 15; c++)
        O[(size_t)(90 + hd * 15 + c) * P + p] = o[c] * rl;
}

// ---------------------------------------------------------------------------
// Fused: out = x + BN(pixel_mixer(x) - x). Circular rolls, group = c % 5.
// ---------------------------------------------------------------------------
__global__ __launch_bounds__(256) void pixmixk(const float* __restrict__ X,
    const float* __restrict__ g, const float* __restrict__ b,
    const float* __restrict__ m, const float* __restrict__ v,
    float* __restrict__ O)
{
    const int idx = blockIdx.x * 256 + threadIdx.x;
    const int c = idx >> 16;
    const int p = idx & 65535;
    const int h = p >> 8, w = p & 255;
    const int j = c % 5;
    int sp;
    if (j == 0)      sp = (h << 8) | ((w + 1) & 255);
    else if (j == 1) sp = (h << 8) | ((w - 1) & 255);
    else if (j == 2) sp = (((h + 1) & 255) << 8) | w;
    else if (j == 3) sp = (((h - 1) & 255) << 8) | w;
    else             sp = p;
    float pm = X[((size_t)c << 16) + sp];
    float xv = X[idx];
    float inv = g[c] * rsqrtf(v[c] + 1e-5f);
    O[idx] = xv + (pm - xv - m[c]) * inv + b[c];
}

extern "C" void kernel_launch(void* const* d_in, const int* in_sizes, int n_in,
                              void* d_out, int out_size, void* d_ws, size_t ws_size,
                              hipStream_t stream)
{
    const float* x        = (const float*)d_in[0];
    const float* a0_qkv_w = (const float*)d_in[1];
    const float* a0_qkv_b = (const float*)d_in[2];
    const float* a0_bn_g  = (const float*)d_in[3];
    const float* a0_bn_b  = (const float*)d_in[4];
    const float* a0_bn_m  = (const float*)d_in[5];
    const float* a0_bn_v  = (const float*)d_in[6];
    const float* a0_proj_w= (const float*)d_in[7];
    const float* a0_proj_b= (const float*)d_in[8];
    const float* a1_qkv_w = (const float*)d_in[9];
    const float* a1_qkv_b = (const float*)d_in[10];
    const float* a1_bn_g  = (const float*)d_in[11];
    const float* a1_bn_b  = (const float*)d_in[12];
    const float* a1_bn_m  = (const float*)d_in[13];
    const float* a1_bn_v  = (const float*)d_in[14];
    const float* a1_proj_w= (const float*)d_in[15];
    const float* a1_proj_b= (const float*)d_in[16];
    const float* t2_bn_g  = (const float*)d_in[17];
    const float* t2_bn_b  = (const float*)d_in[18];
    const float* t2_bn_m  = (const float*)d_in[19];
    const float* t2_bn_v  = (const float*)d_in[20];
    const float* m0_fc1_w = (const float*)d_in[21];
    const float* m0_fc1_b = (const float*)d_in[22];
    const float* m0_fc2_w = (const float*)d_in[23];
    const float* m0_fc2_b = (const float*)d_in[24];
    const float* m1_fc1_w = (const float*)d_in[25];
    const float* m1_fc1_b = (const float*)d_in[26];
    const float* m1_fc2_w = (const float*)d_in[27];
    const float* m1_fc2_b = (const float*)d_in[28];
    const float* m2_fc1_w = (const float*)d_in[29];
    const float* m2_fc1_b = (const float*)d_in[30];
    const float* m2_fc2_w = (const float*)d_in[31];
    const float* m2_fc2_b = (const float*)d_in[32];

    float* W1 = (float*)d_ws;                 // 360 planes (94.4 MB)
    float* W2 = W1 + (size_t)360 * P;         // 180 planes (47.2 MB)
    float* A  = (float*)d_out;                // running x (written fully at each residual)

    dim3 blk(256);
    dim3 g360(64, 18);   // Cout=360: 18 tiles of 20 channels
    dim3 g180(64, 9);    // Cout=180
    dim3 ga(256, 6);

    // ---- stage a0: qkv = BN(conv(x)) -> W1 ----
    convk<180,0,1,0,0><<<g360, blk, 0, stream>>>(x, a0_qkv_w, a0_qkv_b,
        a0_bn_g, a0_bn_b, a0_bn_m, a0_bn_v, nullptr, W1);
    attn8k <<<ga, blk, 0, stream>>>(W1, W2, 0);
    attn16k<<<ga, blk, 0, stream>>>(W1, W2, 0);
    // A = x + proj(attn_out)
    convk<180,0,0,0,1><<<g180, blk, 0, stream>>>(W2, a0_proj_w, a0_proj_b,
        nullptr, nullptr, nullptr, nullptr, x, A);

    // ---- mlp0 ----
    convk<180,1,0,1,0><<<g360, blk, 0, stream>>>(A, m0_fc1_w, m0_fc1_b,
        nullptr, nullptr, nullptr, nullptr, nullptr, W1);
    convk<360,1,0,0,1><<<g180, blk, 0, stream>>>(W1, m0_fc2_w, m0_fc2_b,
        nullptr, nullptr, nullptr, nullptr, A, A);

    // ---- stage a1 (shifts: 4 for ws8, 8 for ws16) ----
    convk<180,0,1,0,0><<<g360, blk, 0, stream>>>(A, a1_qkv_w, a1_qkv_b,
        a1_bn_g, a1_bn_b, a1_bn_m, a1_bn_v, nullptr, W1);
    attn8k <<<ga, blk, 0, stream>>>(W1, W2, 4);
    attn16k<<<ga, blk, 0, stream>>>(W1, W2, 8);
    convk<180,0,0,0,1><<<g180, blk, 0, stream>>>(W2, a1_proj_w, a1_proj_b,
        nullptr, nullptr, nullptr, nullptr, A, A);

    // ---- mlp1 ----
    convk<180,1,0,1,0><<<g360, blk, 0, stream>>>(A, m1_fc1_w, m1_fc1_b,
        nullptr, nullptr, nullptr, nullptr, nullptr, W1);
    convk<360,1,0,0,1><<<g180, blk, 0, stream>>>(W1, m1_fc2_w, m1_fc2_b,
        nullptr, nullptr, nullptr, nullptr, A, A);

    // ---- pixel mixer: W2 = A + BN(pm(A) - A) ----
    pixmixk<<<dim3(180 * 256), blk, 0, stream>>>(A, t2_bn_g, t2_bn_b,
        t2_bn_m, t2_bn_v, W2);

    // ---- mlp2: out(A=d_out) = W2 + fc2(gelu(fc1(W2))) ----
    convk<180,1,0,1,0><<<g360, blk, 0, stream>>>(W2, m2_fc1_w, m2_fc1_b,
        nullptr, nullptr, nullptr, nullptr, nullptr, W1);
    convk<360,1,0,0,1><<<g180, blk, 0, stream>>>(W1, m2_fc2_w, m2_fc2_b,
        nullptr, nullptr, nullptr, nullptr, W2, A);
}

// Round 2
// 1255.892 us; speedup vs baseline: 1.5855x; 1.5855x over previous
//
#include <hip/hip_runtime.h>
#include <math.h>

#define P 65536

typedef float f32x4 __attribute__((ext_vector_type(4)));
typedef short bf16x8 __attribute__((ext_vector_type(8)));
typedef unsigned short us8 __attribute__((ext_vector_type(8)));

__device__ __forceinline__ unsigned short f2b(float f) {
    unsigned u = __builtin_bit_cast(unsigned, f);
    u = (u + 0x7FFFu + ((u >> 16) & 1u)) >> 16;
    return (unsigned short)u;
}
__device__ __forceinline__ float b2f(unsigned short h) {
    return __builtin_bit_cast(float, (unsigned)h << 16);
}
__device__ __forceinline__ int shift_src(int g, int p) {
    int h = p >> 8, w = p & 255;
    if (g == 0) return (w < 255) ? p + 1 : -1;
    if (g == 1) return (w > 0) ? p - 1 : -1;
    if (g == 2) return (h < 255) ? p + 256 : -1;
    if (g == 3) return (h > 0) ? p - 256 : -1;
    return p;
}

// ---------------------------------------------------------------------------
// x [180][65536] fp32 CHW -> A32 [65536][192] fp32 NHWC (pads zeroed)
// ---------------------------------------------------------------------------
__global__ __launch_bounds__(256) void to_nhwc(const float* __restrict__ x,
                                               float* __restrict__ A32) {
    const int p = blockIdx.x * 256 + threadIdx.x;
    #pragma unroll
    for (int c4 = 0; c4 < 45; c4++) {
        float4 v;
        v.x = x[(size_t)(c4 * 4 + 0) * P + p];
        v.y = x[(size_t)(c4 * 4 + 1) * P + p];
        v.z = x[(size_t)(c4 * 4 + 2) * P + p];
        v.w = x[(size_t)(c4 * 4 + 3) * P + p];
        *(float4*)&A32[(size_t)p * 192 + c4 * 4] = v;
    }
    float4 z = make_float4(0, 0, 0, 0);
    *(float4*)&A32[(size_t)p * 192 + 180] = z;
    *(float4*)&A32[(size_t)p * 192 + 184] = z;
    *(float4*)&A32[(size_t)p * 192 + 188] = z;
}

// A32 [65536][192] NHWC -> d_out [180][65536] CHW
__global__ __launch_bounds__(256) void from_nhwc(const float* __restrict__ A32,
                                                 float* __restrict__ out) {
    const int p = blockIdx.x * 256 + threadIdx.x;
    #pragma unroll
    for (int c4 = 0; c4 < 45; c4++) {
        float4 v = *(const float4*)&A32[(size_t)p * 192 + c4 * 4];
        out[(size_t)(c4 * 4 + 0) * P + p] = v.x;
        out[(size_t)(c4 * 4 + 1) * P + p] = v.y;
        out[(size_t)(c4 * 4 + 2) * P + p] = v.z;
        out[(size_t)(c4 * 4 + 3) * P + p] = v.w;
    }
}

// zero pad columns of Qb (ch 360..383) and Ob (ch 180..191)
__global__ __launch_bounds__(256) void padzero(unsigned short* __restrict__ Qb,
                                               unsigned short* __restrict__ Ob) {
    const int p = blockIdx.x * 256 + threadIdx.x;
    us8 z = {0, 0, 0, 0, 0, 0, 0, 0};
    *(us8*)&Qb[(size_t)p * 384 + 360] = z;
    *(us8*)&Qb[(size_t)p * 384 + 368] = z;
    *(us8*)&Qb[(size_t)p * 384 + 376] = z;
    ushort4 z4 = {0, 0, 0, 0};
    *(ushort4*)&Ob[(size_t)p * 192 + 180] = z4;
    *(ushort4*)&Ob[(size_t)p * 192 + 184] = z4;
    *(ushort4*)&Ob[(size_t)p * 192 + 188] = z4;
}

// ---------------------------------------------------------------------------
// MFMA conv1x1: C[pix][oc] = X[pix][k] . W^T[k][oc]  (K padded to 192/384)
// Block: 256 thr = 4 waves (2M x 2N), tile 128 pix x 64 oc, K-chunks of 64.
// SRCB16: input bf16 (stride SSTR) vs fp32 A32 (stride 192).
// SHIFT: shift_plus gather on input (group = cc/(CIN/5), zero borders).
// EPI: 0 = BN affine -> bf16 Qb(384)   1 = bias+GELU -> bf16 Qb(384)
//      2 = bias + fp32 residual(A32) -> A32   3 = bias + bf16 residual(Ob) -> A32
// ---------------------------------------------------------------------------
template<int CIN, int COUT, int SRCB16, int SSTR, int SHIFT, int EPI>
__global__ __launch_bounds__(256) void mconv(
    const void* __restrict__ Xsrc, const float* __restrict__ Wt,
    const float* __restrict__ Bi,
    const float* __restrict__ bg, const float* __restrict__ bb,
    const float* __restrict__ bm, const float* __restrict__ bv,
    const void* __restrict__ Res, void* __restrict__ Out)
{
    constexpr int KP = (CIN == 180) ? 192 : 384;
    constexpr int NCH = KP / 64;
    constexpr int GS = CIN / 5;

    __shared__ __align__(16) unsigned short lx[128][72];
    __shared__ __align__(16) unsigned short lw[64][72];

    const int tid = threadIdx.x;
    const int lane = tid & 63, wid = tid >> 6;
    const int wm = wid >> 1, wn = wid & 1;
    const int pbase = blockIdx.x * 128, nbase = blockIdx.y * 64;

    f32x4 acc[4][2];
    #pragma unroll
    for (int a = 0; a < 4; a++)
        #pragma unroll
        for (int b = 0; b < 2; b++) acc[a][b] = (f32x4){0.f, 0.f, 0.f, 0.f};

    for (int ch = 0; ch < NCH; ++ch) {
        const int kc0 = ch * 64;
        if (ch) __syncthreads();
        // ---- stage W tile [64 oc][64 k] ----
        #pragma unroll
        for (int i = 0; i < 4; i++) {
            int idx = tid + i * 256;
            int row = idx >> 4, c4 = (idx & 15) * 4;
            int oc = nbase + row, cc = kc0 + c4;
            float4 wv = make_float4(0, 0, 0, 0);
            if (oc < COUT && cc < CIN)
                wv = *(const float4*)&Wt[(size_t)oc * CIN + cc];
            ushort4 b4 = {f2b(wv.x), f2b(wv.y), f2b(wv.z), f2b(wv.w)};
            *(ushort4*)&lw[row][c4] = b4;
        }
        // ---- stage X tile [128 pix][64 k] ----
        if constexpr (!SRCB16) {
            const float* X32 = (const float*)Xsrc;
            #pragma unroll
            for (int i = 0; i < 8; i++) {
                int idx = tid + i * 256;
                int row = idx >> 4, c4 = (idx & 15) * 4;
                int cc = kc0 + c4;
                int p = pbase + row;
                float4 xv = make_float4(0, 0, 0, 0);
                if constexpr (SHIFT) {
                    if (cc < CIN) {
                        int sp = shift_src(cc / GS, p);
                        if (sp >= 0) xv = *(const float4*)&X32[(size_t)sp * 192 + cc];
                    }
                } else {
                    xv = *(const float4*)&X32[(size_t)p * 192 + cc]; // pads are 0
                }
                ushort4 b4 = {f2b(xv.x), f2b(xv.y), f2b(xv.z), f2b(xv.w)};
                *(ushort4*)&lx[row][c4] = b4;
            }
        } else {
            const unsigned short* XB = (const unsigned short*)Xsrc;
            #pragma unroll
            for (int i = 0; i < 4; i++) {
                int idx = tid + i * 256;
                int row = idx >> 3, c8 = (idx & 7) * 8;
                int cc = kc0 + c8;
                int p = pbase + row;
                us8 hv = {0, 0, 0, 0, 0, 0, 0, 0};
                if constexpr (SHIFT) {
                    if (cc < CIN) {
                        int sp = shift_src(cc / GS, p);
                        if (sp >= 0) hv = *(const us8*)&XB[(size_t)sp * SSTR + cc];
                    }
                } else {
                    hv = *(const us8*)&XB[(size_t)p * SSTR + cc]; // pads are 0
                }
                *(us8*)&lx[row][c8] = hv;
            }
        }
        __syncthreads();
        // ---- compute: 2 k-steps of 32 ----
        #pragma unroll
        for (int ks = 0; ks < 2; ++ks) {
            const int ko = ks * 32 + (lane >> 4) * 8;
            bf16x8 av[4], bvv[2];
            #pragma unroll
            for (int mf = 0; mf < 4; mf++)
                av[mf] = *(const bf16x8*)&lx[wm * 64 + mf * 16 + (lane & 15)][ko];
            #pragma unroll
            for (int nf = 0; nf < 2; nf++)
                bvv[nf] = *(const bf16x8*)&lw[wn * 32 + nf * 16 + (lane & 15)][ko];
            #pragma unroll
            for (int mf = 0; mf < 4; mf++)
                #pragma unroll
                for (int nf = 0; nf < 2; nf++)
                    acc[mf][nf] = __builtin_amdgcn_mfma_f32_16x16x32_bf16(
                        av[mf], bvv[nf], acc[mf][nf], 0, 0, 0);
        }
    }

    // ---- epilogue ----
    #pragma unroll
    for (int nf = 0; nf < 2; ++nf) {
        const int oc = nbase + wn * 32 + nf * 16 + (lane & 15);
        if (oc >= COUT) continue;
        float sc = 1.f, sh;
        if constexpr (EPI == 0) {
            float inv = bg[oc] * rsqrtf(bv[oc] + 1e-5f);
            sc = inv;
            sh = bb[oc] + (Bi[oc] - bm[oc]) * inv;
        } else {
            sh = Bi[oc];
        }
        #pragma unroll
        for (int mf = 0; mf < 4; ++mf) {
            #pragma unroll
            for (int r = 0; r < 4; ++r) {
                const int pix = pbase + wm * 64 + mf * 16 + (lane >> 4) * 4 + r;
                float y = acc[mf][nf][r] * sc + sh;
                if constexpr (EPI == 1)
                    y = 0.5f * y * (1.f + erff(y * 0.70710678118654752f));
                if constexpr (EPI <= 1) {
                    ((unsigned short*)Out)[(size_t)pix * 384 + oc] = f2b(y);
                } else if constexpr (EPI == 2) {
                    y += ((const float*)Res)[(size_t)pix * 192 + oc];
                    ((float*)Out)[(size_t)pix * 192 + oc] = y;
                } else {
                    y += b2f(((const unsigned short*)Res)[(size_t)pix * 192 + oc]);
                    ((float*)Out)[(size_t)pix * 192 + oc] = y;
                }
            }
        }
    }
}

// ---------------------------------------------------------------------------
// Window attention, 8x8 (slice0: q ch [0,90), v ch [90,180) of Qb).
// Wave per window, 4 windows/block. Out -> Ob ch [0,90).
// ---------------------------------------------------------------------------
__global__ __launch_bounds__(256) void attn8k(const unsigned short* __restrict__ Qb,
                                              unsigned short* __restrict__ Ob, int sh)
{
    const int tid = threadIdx.x;
    const int wi = tid >> 6, lane = tid & 63;
    const int win = blockIdx.x * 4 + wi;
    const int hd = blockIdx.y;
    const int wy = win >> 5, wx = win & 31;
    const int ty = lane >> 3, tx = lane & 7;
    const int gh = (wy * 8 + ty - sh) & 255;
    const int gw = (wx * 8 + tx - sh) & 255;
    const int p = (gh << 8) | gw;

    __shared__ float q_s[4][64][16];
    __shared__ float v_s[4][64][16];

    const unsigned short* Q = Qb + (size_t)p * 384 + hd * 15;
    #pragma unroll
    for (int c = 0; c < 15; c++) {
        q_s[wi][lane][c] = b2f(Q[c]);
        v_s[wi][lane][c] = b2f(Q[90 + c]);
    }
    q_s[wi][lane][15] = 0.f;
    v_s[wi][lane][15] = 0.f;
    __syncthreads();

    float qi[16];
    #pragma unroll
    for (int c = 0; c < 16; c++) qi[c] = q_s[wi][lane][c];

    float s[64];
    for (int j = 0; j < 64; j++) {
        const float4* qr = reinterpret_cast<const float4*>(q_s[wi][j]);
        float d = 0.f;
        #pragma unroll
        for (int c4 = 0; c4 < 4; c4++) {
            float4 a = qr[c4];
            d = fmaf(qi[c4 * 4 + 0], a.x, d);
            d = fmaf(qi[c4 * 4 + 1], a.y, d);
            d = fmaf(qi[c4 * 4 + 2], a.z, d);
            d = fmaf(qi[c4 * 4 + 3], a.w, d);
        }
        s[j] = d;
    }
    float mx = s[0];
    for (int j = 1; j < 64; j++) mx = fmaxf(mx, s[j]);
    float l = 0.f;
    for (int j = 0; j < 64; j++) { s[j] = __expf(s[j] - mx); l += s[j]; }

    float o[16];
    #pragma unroll
    for (int c = 0; c < 16; c++) o[c] = 0.f;
    for (int j = 0; j < 64; j++) {
        const float4* vr = reinterpret_cast<const float4*>(v_s[wi][j]);
        #pragma unroll
        for (int c4 = 0; c4 < 4; c4++) {
            float4 a = vr[c4];
            o[c4 * 4 + 0] = fmaf(s[j], a.x, o[c4 * 4 + 0]);
            o[c4 * 4 + 1] = fmaf(s[j], a.y, o[c4 * 4 + 1]);
            o[c4 * 4 + 2] = fmaf(s[j], a.z, o[c4 * 4 + 2]);
            o[c4 * 4 + 3] = fmaf(s[j], a.w, o[c4 * 4 + 3]);
        }
    }
    float rl = 1.f / l;
    #pragma unroll
    for (int c = 0; c < 15; c++)
        Ob[(size_t)p * 192 + hd * 15 + c] = f2b(o[c] * rl);
}

// ---------------------------------------------------------------------------
// Window attention, 16x16 (slice1: q ch [180,270), v ch [270,360) of Qb).
// Block per window (256 tokens). Out -> Ob ch [90,180).
// ---------------------------------------------------------------------------
__global__ __launch_bounds__(256) void attn16k(const unsigned short* __restrict__ Qb,
                                               unsigned short* __restrict__ Ob, int sh)
{
    const int tid = threadIdx.x;
    const int win = blockIdx.x;
    const int hd = blockIdx.y;
    const int wy = win >> 4, wx = win & 15;
    const int ty = tid >> 4, tx = tid & 15;
    const int gh = (wy * 16 + ty - sh) & 255;
    const int gw = (wx * 16 + tx - sh) & 255;
    const int p = (gh << 8) | gw;

    __shared__ float q_s[256][16];
    __shared__ float v_s[256][16];

    const unsigned short* Q = Qb + (size_t)p * 384 + 180 + hd * 15;
    #pragma unroll
    for (int c = 0; c < 15; c++) {
        q_s[tid][c] = b2f(Q[c]);
        v_s[tid][c] = b2f(Q[90 + c]);
    }
    q_s[tid][15] = 0.f;
    v_s[tid][15] = 0.f;
    __syncthreads();

    float qi[16];
    #pragma unroll
    for (int c = 0; c < 16; c++) qi[c] = q_s[tid][c];

    float m = -3.0e38f, l = 0.f;
    float o[16];
    #pragma unroll
    for (int c = 0; c < 16; c++) o[c] = 0.f;

    for (int jc = 0; jc < 4; jc++) {
        float s[64];
        float cm = -3.0e38f;
        for (int jj = 0; jj < 64; jj++) {
            const int j = jc * 64 + jj;
            const float4* qr = reinterpret_cast<const float4*>(q_s[j]);
            float d = 0.f;
            #pragma unroll
            for (int c4 = 0; c4 < 4; c4++) {
                float4 a = qr[c4];
                d = fmaf(qi[c4 * 4 + 0], a.x, d);
                d = fmaf(qi[c4 * 4 + 1], a.y, d);
                d = fmaf(qi[c4 * 4 + 2], a.z, d);
                d = fmaf(qi[c4 * 4 + 3], a.w, d);
            }
            s[jj] = d;
            cm = fmaxf(cm, d);
        }
        float nm = fmaxf(m, cm);
        float rs = __expf(m - nm);
        l *= rs;
        #pragma unroll
        for (int c = 0; c < 16; c++) o[c] *= rs;
        for (int jj = 0; jj < 64; jj++) {
            float e = __expf(s[jj] - nm);
            l += e;
            const float4* vr = reinterpret_cast<const float4*>(v_s[jc * 64 + jj]);
            #pragma unroll
            for (int c4 = 0; c4 < 4; c4++) {
                float4 a = vr[c4];
                o[c4 * 4 + 0] = fmaf(e, a.x, o[c4 * 4 + 0]);
                o[c4 * 4 + 1] = fmaf(e, a.y, o[c4 * 4 + 1]);
                o[c4 * 4 + 2] = fmaf(e, a.z, o[c4 * 4 + 2]);
                o[c4 * 4 + 3] = fmaf(e, a.w, o[c4 * 4 + 3]);
            }
        }
        m = nm;
    }
    float rl = 1.f / l;
    #pragma unroll
    for (int c = 0; c < 15; c++)
        Ob[(size_t)p * 192 + 90 + hd * 15 + c] = f2b(o[c] * rl);
}

// ---------------------------------------------------------------------------
// pixel mixer: Ob = bf16( x + BN(pm(x) - x) ), x = A32 (NHWC). Circular rolls.
// ---------------------------------------------------------------------------
__global__ __launch_bounds__(256) void pixmixk(const float* __restrict__ A32,
    const float* __restrict__ g, const float* __restrict__ b,
    const float* __restrict__ m, const float* __restrict__ v,
    unsigned short* __restrict__ Ob)
{
    const int idx = blockIdx.x * 256 + threadIdx.x; // 65536*45
    const int p = idx / 45;
    const int c0 = (idx - p * 45) * 4;
    const int h = p >> 8, w = p & 255;
    float4 x = *(const float4*)&A32[(size_t)p * 192 + c0];
    ushort4 o;
    #pragma unroll
    for (int j = 0; j < 4; j++) {
        int c = c0 + j;
        int gr = c - (c / 5) * 5;
        int sp;
        if (gr == 0)      sp = (h << 8) | ((w + 1) & 255);
        else if (gr == 1) sp = (h << 8) | ((w - 1) & 255);
        else if (gr == 2) sp = (((h + 1) & 255) << 8) | w;
        else if (gr == 3) sp = (((h - 1) & 255) << 8) | w;
        else              sp = p;
        float pm = A32[(size_t)sp * 192 + c];
        float xv = (j == 0) ? x.x : (j == 1) ? x.y : (j == 2) ? x.z : x.w;
        float inv = g[c] * rsqrtf(v[c] + 1e-5f);
        float y = xv + (pm - xv - m[c]) * inv + b[c];
        ((unsigned short*)&o)[j] = f2b(y);
    }
    *(ushort4*)&Ob[(size_t)p * 192 + c0] = o;
}

extern "C" void kernel_launch(void* const* d_in, const int* in_sizes, int n_in,
                              void* d_out, int out_size, void* d_ws, size_t ws_size,
                              hipStream_t stream)
{
    const float* x        = (const float*)d_in[0];
    const float* a0_qkv_w = (const float*)d_in[1];
    const float* a0_qkv_b = (const float*)d_in[2];
    const float* a0_bn_g  = (const float*)d_in[3];
    const float* a0_bn_b  = (const float*)d_in[4];
    const float* a0_bn_m  = (const float*)d_in[5];
    const float* a0_bn_v  = (const float*)d_in[6];
    const float* a0_proj_w= (const float*)d_in[7];
    const float* a0_proj_b= (const float*)d_in[8];
    const float* a1_qkv_w = (const float*)d_in[9];
    const float* a1_qkv_b = (const float*)d_in[10];
    const float* a1_bn_g  = (const float*)d_in[11];
    const float* a1_bn_b  = (const float*)d_in[12];
    const float* a1_bn_m  = (const float*)d_in[13];
    const float* a1_bn_v  = (const float*)d_in[14];
    const float* a1_proj_w= (const float*)d_in[15];
    const float* a1_proj_b= (const float*)d_in[16];
    const float* t2_bn_g  = (const float*)d_in[17];
    const float* t2_bn_b  = (const float*)d_in[18];
    const float* t2_bn_m  = (const float*)d_in[19];
    const float* t2_bn_v  = (const float*)d_in[20];
    const float* m0_fc1_w = (const float*)d_in[21];
    const float* m0_fc1_b = (const float*)d_in[22];
    const float* m0_fc2_w = (const float*)d_in[23];
    const float* m0_fc2_b = (const float*)d_in[24];
    const float* m1_fc1_w = (const float*)d_in[25];
    const float* m1_fc1_b = (const float*)d_in[26];
    const float* m1_fc2_w = (const float*)d_in[27];
    const float* m1_fc2_b = (const float*)d_in[28];
    const float* m2_fc1_w = (const float*)d_in[29];
    const float* m2_fc1_b = (const float*)d_in[30];
    const float* m2_fc2_w = (const float*)d_in[31];
    const float* m2_fc2_b = (const float*)d_in[32];

    unsigned short* Qb = (unsigned short*)d_ws;                    // [P][384] bf16
    unsigned short* Ob = Qb + (size_t)P * 384;                     // [P][192] bf16
    float*          A32 = (float*)(Ob + (size_t)P * 192);          // [P][192] fp32

    dim3 blk(256);
    dim3 gpix(256);
    dim3 g360(512, 6);
    dim3 g180(512, 3);
    dim3 ga8(256, 6);
    dim3 ga16(256, 6);

    padzero<<<gpix, blk, 0, stream>>>(Qb, Ob);
    to_nhwc<<<gpix, blk, 0, stream>>>(x, A32);

    // ---- attn stage 0 ----
    mconv<180,360,0,192,0,0><<<g360, blk, 0, stream>>>(A32, a0_qkv_w, a0_qkv_b,
        a0_bn_g, a0_bn_b, a0_bn_m, a0_bn_v, nullptr, Qb);
    attn8k <<<ga8,  blk, 0, stream>>>(Qb, Ob, 0);
    attn16k<<<ga16, blk, 0, stream>>>(Qb, Ob, 0);
    mconv<180,180,1,192,0,2><<<g180, blk, 0, stream>>>(Ob, a0_proj_w, a0_proj_b,
        nullptr, nullptr, nullptr, nullptr, A32, A32);

    // ---- mlp0 ----
    mconv<180,360,0,192,1,1><<<g360, blk, 0, stream>>>(A32, m0_fc1_w, m0_fc1_b,
        nullptr, nullptr, nullptr, nullptr, nullptr, Qb);
    mconv<360,180,1,384,1,2><<<g180, blk, 0, stream>>>(Qb, m0_fc2_w, m0_fc2_b,
        nullptr, nullptr, nullptr, nullptr, A32, A32);

    // ---- attn stage 1 ----
    mconv<180,360,0,192,0,0><<<g360, blk, 0, stream>>>(A32, a1_qkv_w, a1_qkv_b,
        a1_bn_g, a1_bn_b, a1_bn_m, a1_bn_v, nullptr, Qb);
    attn8k <<<ga8,  blk, 0, stream>>>(Qb, Ob, 4);
    attn16k<<<ga16, blk, 0, stream>>>(Qb, Ob, 8);
    mconv<180,180,1,192,0,2><<<g180, blk, 0, stream>>>(Ob, a1_proj_w, a1_proj_b,
        nullptr, nullptr, nullptr, nullptr, A32, A32);

    // ---- mlp1 ----
    mconv<180,360,0,192,1,1><<<g360, blk, 0, stream>>>(A32, m1_fc1_w, m1_fc1_b,
        nullptr, nullptr, nullptr, nullptr, nullptr, Qb);
    mconv<360,180,1,384,1,2><<<g180, blk, 0, stream>>>(Qb, m1_fc2_w, m1_fc2_b,
        nullptr, nullptr, nullptr, nullptr, A32, A32);

    // ---- pixel mixer: Ob = bf16(x5) ----
    pixmixk<<<dim3(65536 * 45 / 256), blk, 0, stream>>>(A32, t2_bn_g, t2_bn_b,
        t2_bn_m, t2_bn_v, Ob);

    // ---- mlp2 (input/residual = Ob bf16) ----
    mconv<180,360,1,192,1,1><<<g360, blk, 0, stream>>>(Ob, m2_fc1_w, m2_fc1_b,
        nullptr, nullptr, nullptr, nullptr, nullptr, Qb);
    mconv<360,180,1,384,1,3><<<g180, blk, 0, stream>>>(Qb, m2_fc2_w, m2_fc2_b,
        nullptr, nullptr, nullptr, nullptr, Ob, A32);

    from_nhwc<<<gpix, blk, 0, stream>>>(A32, (float*)d_out);
}

// Round 3
// 848.700 us; speedup vs baseline: 2.3462x; 1.4798x over previous
//
#include <hip/hip_runtime.h>
#include <math.h>

#define P 65536

typedef float f32x4 __attribute__((ext_vector_type(4)));
typedef float f32x16 __attribute__((ext_vector_type(16)));
typedef short bf16x8 __attribute__((ext_vector_type(8)));
typedef unsigned short us8 __attribute__((ext_vector_type(8)));

__device__ __forceinline__ unsigned short f2b(float f) {
    unsigned u = __builtin_bit_cast(unsigned, f);
    u = (u + 0x7FFFu + ((u >> 16) & 1u)) >> 16;
    return (unsigned short)u;
}
__device__ __forceinline__ float b2f(unsigned short h) {
    return __builtin_bit_cast(float, (unsigned)h << 16);
}
__device__ __forceinline__ int shift_src(int g, int p) {
    int h = p >> 8, w = p & 255;
    if (g == 0) return (w < 255) ? p + 1 : -1;
    if (g == 1) return (w > 0) ? p - 1 : -1;
    if (g == 2) return (h < 255) ? p + 256 : -1;
    if (g == 3) return (h > 0) ? p - 256 : -1;
    return p;
}

// ---------------------------------------------------------------------------
// x [180][65536] fp32 CHW -> A32 [65536][192] fp32 NHWC (pads zeroed)
// ---------------------------------------------------------------------------
__global__ __launch_bounds__(256) void to_nhwc(const float* __restrict__ x,
                                               float* __restrict__ A32) {
    const int p = blockIdx.x * 256 + threadIdx.x;
    #pragma unroll
    for (int c4 = 0; c4 < 45; c4++) {
        float4 v;
        v.x = x[(size_t)(c4 * 4 + 0) * P + p];
        v.y = x[(size_t)(c4 * 4 + 1) * P + p];
        v.z = x[(size_t)(c4 * 4 + 2) * P + p];
        v.w = x[(size_t)(c4 * 4 + 3) * P + p];
        *(float4*)&A32[(size_t)p * 192 + c4 * 4] = v;
    }
    float4 z = make_float4(0, 0, 0, 0);
    *(float4*)&A32[(size_t)p * 192 + 180] = z;
    *(float4*)&A32[(size_t)p * 192 + 184] = z;
    *(float4*)&A32[(size_t)p * 192 + 188] = z;
}

// A32 [65536][192] NHWC -> d_out [180][65536] CHW
__global__ __launch_bounds__(256) void from_nhwc(const float* __restrict__ A32,
                                                 float* __restrict__ out) {
    const int p = blockIdx.x * 256 + threadIdx.x;
    #pragma unroll
    for (int c4 = 0; c4 < 45; c4++) {
        float4 v = *(const float4*)&A32[(size_t)p * 192 + c4 * 4];
        out[(size_t)(c4 * 4 + 0) * P + p] = v.x;
        out[(size_t)(c4 * 4 + 1) * P + p] = v.y;
        out[(size_t)(c4 * 4 + 2) * P + p] = v.z;
        out[(size_t)(c4 * 4 + 3) * P + p] = v.w;
    }
}

// zero pad columns of Qb (ch 360..383) and Ob (ch 180..191)
__global__ __launch_bounds__(256) void padzero(unsigned short* __restrict__ Qb,
                                               unsigned short* __restrict__ Ob) {
    const int p = blockIdx.x * 256 + threadIdx.x;
    us8 z = {0, 0, 0, 0, 0, 0, 0, 0};
    *(us8*)&Qb[(size_t)p * 384 + 360] = z;
    *(us8*)&Qb[(size_t)p * 384 + 368] = z;
    *(us8*)&Qb[(size_t)p * 384 + 376] = z;
    ushort4 z4 = {0, 0, 0, 0};
    *(ushort4*)&Ob[(size_t)p * 192 + 180] = z4;
    *(ushort4*)&Ob[(size_t)p * 192 + 184] = z4;
    *(ushort4*)&Ob[(size_t)p * 192 + 188] = z4;
}

// ---------------------------------------------------------------------------
// MFMA conv1x1: C[pix][oc] = X[pix][k] . W^T[k][oc]  (K padded to 192/384)
// Block: 256 thr = 4 waves (2M x 2N), tile 128 pix x 64 oc, K-chunks of 64.
// ---------------------------------------------------------------------------
template<int CIN, int COUT, int SRCB16, int SSTR, int SHIFT, int EPI>
__global__ __launch_bounds__(256) void mconv(
    const void* __restrict__ Xsrc, const float* __restrict__ Wt,
    const float* __restrict__ Bi,
    const float* __restrict__ bg, const float* __restrict__ bb,
    const float* __restrict__ bm, const float* __restrict__ bv,
    const void* __restrict__ Res, void* __restrict__ Out)
{
    constexpr int KP = (CIN == 180) ? 192 : 384;
    constexpr int NCH = KP / 64;
    constexpr int GS = CIN / 5;

    __shared__ __align__(16) unsigned short lx[128][72];
    __shared__ __align__(16) unsigned short lw[64][72];

    const int tid = threadIdx.x;
    const int lane = tid & 63, wid = tid >> 6;
    const int wm = wid >> 1, wn = wid & 1;
    const int pbase = blockIdx.x * 128, nbase = blockIdx.y * 64;

    f32x4 acc[4][2];
    #pragma unroll
    for (int a = 0; a < 4; a++)
        #pragma unroll
        for (int b = 0; b < 2; b++) acc[a][b] = (f32x4){0.f, 0.f, 0.f, 0.f};

    for (int ch = 0; ch < NCH; ++ch) {
        const int kc0 = ch * 64;
        if (ch) __syncthreads();
        #pragma unroll
        for (int i = 0; i < 4; i++) {
            int idx = tid + i * 256;
            int row = idx >> 4, c4 = (idx & 15) * 4;
            int oc = nbase + row, cc = kc0 + c4;
            float4 wv = make_float4(0, 0, 0, 0);
            if (oc < COUT && cc < CIN)
                wv = *(const float4*)&Wt[(size_t)oc * CIN + cc];
            ushort4 b4 = {f2b(wv.x), f2b(wv.y), f2b(wv.z), f2b(wv.w)};
            *(ushort4*)&lw[row][c4] = b4;
        }
        if constexpr (!SRCB16) {
            const float* X32 = (const float*)Xsrc;
            #pragma unroll
            for (int i = 0; i < 8; i++) {
                int idx = tid + i * 256;
                int row = idx >> 4, c4 = (idx & 15) * 4;
                int cc = kc0 + c4;
                int p = pbase + row;
                float4 xv = make_float4(0, 0, 0, 0);
                if constexpr (SHIFT) {
                    if (cc < CIN) {
                        int sp = shift_src(cc / GS, p);
                        if (sp >= 0) xv = *(const float4*)&X32[(size_t)sp * 192 + cc];
                    }
                } else {
                    xv = *(const float4*)&X32[(size_t)p * 192 + cc];
                }
                ushort4 b4 = {f2b(xv.x), f2b(xv.y), f2b(xv.z), f2b(xv.w)};
                *(ushort4*)&lx[row][c4] = b4;
            }
        } else {
            const unsigned short* XB = (const unsigned short*)Xsrc;
            #pragma unroll
            for (int i = 0; i < 4; i++) {
                int idx = tid + i * 256;
                int row = idx >> 3, c8 = (idx & 7) * 8;
                int cc = kc0 + c8;
                int p = pbase + row;
                us8 hv = {0, 0, 0, 0, 0, 0, 0, 0};
                if constexpr (SHIFT) {
                    if (cc < CIN) {
                        int sp = shift_src(cc / GS, p);
                        if (sp >= 0) hv = *(const us8*)&XB[(size_t)sp * SSTR + cc];
                    }
                } else {
                    hv = *(const us8*)&XB[(size_t)p * SSTR + cc];
                }
                *(us8*)&lx[row][c8] = hv;
            }
        }
        __syncthreads();
        #pragma unroll
        for (int ks = 0; ks < 2; ++ks) {
            const int ko = ks * 32 + (lane >> 4) * 8;
            bf16x8 av[4], bvv[2];
            #pragma unroll
            for (int mf = 0; mf < 4; mf++)
                av[mf] = *(const bf16x8*)&lx[wm * 64 + mf * 16 + (lane & 15)][ko];
            #pragma unroll
            for (int nf = 0; nf < 2; nf++)
                bvv[nf] = *(const bf16x8*)&lw[wn * 32 + nf * 16 + (lane & 15)][ko];
            #pragma unroll
            for (int mf = 0; mf < 4; mf++)
                #pragma unroll
                for (int nf = 0; nf < 2; nf++)
                    acc[mf][nf] = __builtin_amdgcn_mfma_f32_16x16x32_bf16(
                        av[mf], bvv[nf], acc[mf][nf], 0, 0, 0);
        }
    }

    #pragma unroll
    for (int nf = 0; nf < 2; ++nf) {
        const int oc = nbase + wn * 32 + nf * 16 + (lane & 15);
        if (oc >= COUT) continue;
        float sc = 1.f, sh;
        if constexpr (EPI == 0) {
            float inv = bg[oc] * rsqrtf(bv[oc] + 1e-5f);
            sc = inv;
            sh = bb[oc] + (Bi[oc] - bm[oc]) * inv;
        } else {
            sh = Bi[oc];
        }
        #pragma unroll
        for (int mf = 0; mf < 4; ++mf) {
            #pragma unroll
            for (int r = 0; r < 4; ++r) {
                const int pix = pbase + wm * 64 + mf * 16 + (lane >> 4) * 4 + r;
                float y = acc[mf][nf][r] * sc + sh;
                if constexpr (EPI == 1)
                    y = 0.5f * y * (1.f + erff(y * 0.70710678118654752f));
                if constexpr (EPI <= 1) {
                    ((unsigned short*)Out)[(size_t)pix * 384 + oc] = f2b(y);
                } else if constexpr (EPI == 2) {
                    y += ((const float*)Res)[(size_t)pix * 192 + oc];
                    ((float*)Out)[(size_t)pix * 192 + oc] = y;
                } else {
                    y += b2f(((const unsigned short*)Res)[(size_t)pix * 192 + oc]);
                    ((float*)Out)[(size_t)pix * 192 + oc] = y;
                }
            }
        }
    }
}

// ---------------------------------------------------------------------------
// MFMA window attention via symmetric-S trick.
// S = Q.Q^T is exactly symmetric, so the 32x32x16 MFMA C-layout
// (col=lane&31, row=(reg&3)+8*(reg>>2)+4*(lane>>5)) reinterprets as
// row=lane&31 (lane owns a full S-row) -> lane-local softmax + one shfl_xor(32).
// PV computed as (PV)^T = V^T . P^T ; P rows feed B-fragments after a
// 2x shfl_xor(32) half-lane word exchange. Flash-style online softmax over mi.
// WSZ=8: wave per window-head (4/block). WSZ=16: block per window-head.
// ---------------------------------------------------------------------------
template<int WSZ>
__global__ __launch_bounds__(256) void mattn(const unsigned short* __restrict__ Qb,
                                             unsigned short* __restrict__ Ob, int sh)
{
    constexpr int TOK = WSZ * WSZ;
    constexpr int WPB = (WSZ == 8) ? 4 : 1;
    constexpr int NMI = TOK / 32;

    __shared__ __align__(16) unsigned short q_s[WPB][TOK][24];
    __shared__ __align__(16) unsigned short v_s[WPB][TOK][16];

    const int tid = threadIdx.x;
    const int lane = tid & 63, wid = tid >> 6;
    const int la = lane & 31, h = lane >> 5;
    const int head = blockIdx.y;
    const int qoff = ((WSZ == 8) ? 0 : 180) + head * 15;
    const int voff = qoff + 90;
    const int obase = ((WSZ == 8) ? 0 : 90) + head * 15;

    const int win = (WSZ == 8) ? (blockIdx.x * 4 + wid) : blockIdx.x;
    const int wy = win >> ((WSZ == 8) ? 5 : 4);
    const int wx = win & ((WSZ == 8) ? 31 : 15);

    // ---- stage Q, V (token-major, q rows padded to 24 for aligned b128) ----
    {
        const int sw = (WSZ == 8) ? wid : 0;
        const int t = (WSZ == 8) ? (tid & 63) : tid;
        const int ty = t / WSZ, tx = t % WSZ;
        const int gh = (wy * WSZ + ty - sh) & 255;
        const int gw = (wx * WSZ + tx - sh) & 255;
        const unsigned short* src = Qb + (size_t)((gh << 8) | gw) * 384;
        #pragma unroll
        for (int c = 0; c < 15; c++) {
            q_s[sw][t][c] = src[qoff + c];
            v_s[sw][t][c] = src[voff + c];
        }
        q_s[sw][t][15] = 0;
        v_s[sw][t][15] = 0;
    }
    __syncthreads();

    const int mywin = (WSZ == 8) ? wid : 0;
    const unsigned short (*qs)[24] = q_s[mywin];
    const unsigned short (*vs)[16] = v_s[mywin];
    const int ni0 = (WSZ == 8) ? 0 : (wid * 2);
    const int ni1 = ni0 + 1;

    // B-fragments for S (cols = the wave's two row-groups) — loop-invariant
    bf16x8 bfr0 = *(const bf16x8*)&qs[ni0 * 32 + la][h * 8];
    bf16x8 bfr1 = *(const bf16x8*)&qs[ni1 * 32 + la][h * 8];

    f32x16 O0, O1;
    #pragma unroll
    for (int r = 0; r < 16; r++) { O0[r] = 0.f; O1[r] = 0.f; }
    float m0 = -3.0e38f, m1 = -3.0e38f, l0 = 0.f, l1 = 0.f;

    unsigned short hw0[16], hw1[16];

    // online-softmax update: S-tile -> rescale O,l; produce rounded-bf16 P
    auto proc = [&](f32x16& S, float& m, float& l, f32x16& O, unsigned short* hw) {
        float vm = S[0];
        #pragma unroll
        for (int r = 1; r < 16; r++) vm = fmaxf(vm, S[r]);
        vm = fmaxf(vm, __shfl_xor(vm, 32));
        float nm = fmaxf(m, vm);
        float rs = __expf(m - nm);
        m = nm;
        l *= rs;
        #pragma unroll
        for (int r = 0; r < 16; r++) O[r] *= rs;
        float lacc = 0.f;
        #pragma unroll
        for (int r = 0; r < 16; r++) {
            unsigned short u = f2b(__expf(S[r] - nm));
            hw[r] = u;
            lacc += b2f(u);
        }
        l += lacc;
    };

    // P -> B-fragment for k-step sub (half-lane word exchange via shfl_xor 32)
    auto pack = [&](const unsigned short* hw, int sub) -> bf16x8 {
        unsigned A01 = (unsigned)hw[8 * sub + 0] | ((unsigned)hw[8 * sub + 1] << 16);
        unsigned A23 = (unsigned)hw[8 * sub + 2] | ((unsigned)hw[8 * sub + 3] << 16);
        unsigned B01 = (unsigned)hw[8 * sub + 4] | ((unsigned)hw[8 * sub + 5] << 16);
        unsigned B23 = (unsigned)hw[8 * sub + 6] | ((unsigned)hw[8 * sub + 7] << 16);
        unsigned x1 = (unsigned)__shfl_xor((int)(h ? A01 : B01), 32);
        unsigned x2 = (unsigned)__shfl_xor((int)(h ? A23 : B23), 32);
        union { unsigned u[4]; bf16x8 v; } pf;
        pf.u[0] = h ? x1 : A01;
        pf.u[1] = h ? x2 : A23;
        pf.u[2] = h ? B01 : x1;
        pf.u[3] = h ? B23 : x2;
        return pf.v;
    };

    for (int mi = 0; mi < NMI; ++mi) {
        bf16x8 af = *(const bf16x8*)&qs[mi * 32 + la][h * 8];
        f32x16 z;
        #pragma unroll
        for (int r = 0; r < 16; r++) z[r] = 0.f;
        f32x16 s0 = __builtin_amdgcn_mfma_f32_32x32x16_bf16(af, bfr0, z, 0, 0, 0);
        f32x16 s1 = __builtin_amdgcn_mfma_f32_32x32x16_bf16(af, bfr1, z, 0, 0, 0);

        proc(s0, m0, l0, O0, hw0);
        proc(s1, m1, l1, O1, hw1);

        #pragma unroll
        for (int sub = 0; sub < 2; ++sub) {
            // A-fragment: V^T rows = channels, k = tokens of this 16-chunk
            union { unsigned short us[8]; bf16x8 v; } av;
            #pragma unroll
            for (int j = 0; j < 8; j++)
                av.us[j] = vs[mi * 32 + sub * 16 + h * 8 + j][la & 15];
            bf16x8 pf0 = pack(hw0, sub);
            bf16x8 pf1 = pack(hw1, sub);
            O0 = __builtin_amdgcn_mfma_f32_32x32x16_bf16(av.v, pf0, O0, 0, 0, 0);
            O1 = __builtin_amdgcn_mfma_f32_32x32x16_bf16(av.v, pf1, O1, 0, 0, 0);
        }
    }

    // ---- normalize + write (C rows = channels, cols = tokens) ----
    #pragma unroll
    for (int t = 0; t < 2; ++t) {
        const f32x16& O = t ? O1 : O0;
        float l = t ? l1 : l0;
        const int ni = t ? ni1 : ni0;
        float lt = l + __shfl_xor(l, 32);
        float inv = 1.f / lt;
        const int R = ni * 32 + la;
        const int ty = R / WSZ, tx = R % WSZ;
        const int gh = (wy * WSZ + ty - sh) & 255;
        const int gw = (wx * WSZ + tx - sh) & 255;
        unsigned short* dst = Ob + (size_t)((gh << 8) | gw) * 192 + obase;
        #pragma unroll
        for (int reg = 0; reg < 16; ++reg) {
            const int ch = (reg & 3) + 8 * (reg >> 2) + 4 * h;
            if (ch < 15) dst[ch] = f2b(O[reg] * inv);
        }
    }
}

// ---------------------------------------------------------------------------
// pixel mixer: Ob = bf16( x + BN(pm(x) - x) ), x = A32 (NHWC). Circular rolls.
// ---------------------------------------------------------------------------
__global__ __launch_bounds__(256) void pixmixk(const float* __restrict__ A32,
    const float* __restrict__ g, const float* __restrict__ b,
    const float* __restrict__ m, const float* __restrict__ v,
    unsigned short* __restrict__ Ob)
{
    const int idx = blockIdx.x * 256 + threadIdx.x; // 65536*45
    const int p = idx / 45;
    const int c0 = (idx - p * 45) * 4;
    const int h = p >> 8, w = p & 255;
    float4 x = *(const float4*)&A32[(size_t)p * 192 + c0];
    ushort4 o;
    #pragma unroll
    for (int j = 0; j < 4; j++) {
        int c = c0 + j;
        int gr = c - (c / 5) * 5;
        int sp;
        if (gr == 0)      sp = (h << 8) | ((w + 1) & 255);
        else if (gr == 1) sp = (h << 8) | ((w - 1) & 255);
        else if (gr == 2) sp = (((h + 1) & 255) << 8) | w;
        else if (gr == 3) sp = (((h - 1) & 255) << 8) | w;
        else              sp = p;
        float pm = A32[(size_t)sp * 192 + c];
        float xv = (j == 0) ? x.x : (j == 1) ? x.y : (j == 2) ? x.z : x.w;
        float inv = g[c] * rsqrtf(v[c] + 1e-5f);
        float y = xv + (pm - xv - m[c]) * inv + b[c];
        ((unsigned short*)&o)[j] = f2b(y);
    }
    *(ushort4*)&Ob[(size_t)p * 192 + c0] = o;
}

extern "C" void kernel_launch(void* const* d_in, const int* in_sizes, int n_in,
                              void* d_out, int out_size, void* d_ws, size_t ws_size,
                              hipStream_t stream)
{
    const float* x        = (const float*)d_in[0];
    const float* a0_qkv_w = (const float*)d_in[1];
    const float* a0_qkv_b = (const float*)d_in[2];
    const float* a0_bn_g  = (const float*)d_in[3];
    const float* a0_bn_b  = (const float*)d_in[4];
    const float* a0_bn_m  = (const float*)d_in[5];
    const float* a0_bn_v  = (const float*)d_in[6];
    const float* a0_proj_w= (const float*)d_in[7];
    const float* a0_proj_b= (const float*)d_in[8];
    const float* a1_qkv_w = (const float*)d_in[9];
    const float* a1_qkv_b = (const float*)d_in[10];
    const float* a1_bn_g  = (const float*)d_in[11];
    const float* a1_bn_b  = (const float*)d_in[12];
    const float* a1_bn_m  = (const float*)d_in[13];
    const float* a1_bn_v  = (const float*)d_in[14];
    const float* a1_proj_w= (const float*)d_in[15];
    const float* a1_proj_b= (const float*)d_in[16];
    const float* t2_bn_g  = (const float*)d_in[17];
    const float* t2_bn_b  = (const float*)d_in[18];
    const float* t2_bn_m  = (const float*)d_in[19];
    const float* t2_bn_v  = (const float*)d_in[20];
    const float* m0_fc1_w = (const float*)d_in[21];
    const float* m0_fc1_b = (const float*)d_in[22];
    const float* m0_fc2_w = (const float*)d_in[23];
    const float* m0_fc2_b = (const float*)d_in[24];
    const float* m1_fc1_w = (const float*)d_in[25];
    const float* m1_fc1_b = (const float*)d_in[26];
    const float* m1_fc2_w = (const float*)d_in[27];
    const float* m1_fc2_b = (const float*)d_in[28];
    const float* m2_fc1_w = (const float*)d_in[29];
    const float* m2_fc1_b = (const float*)d_in[30];
    const float* m2_fc2_w = (const float*)d_in[31];
    const float* m2_fc2_b = (const float*)d_in[32];

    unsigned short* Qb = (unsigned short*)d_ws;                    // [P][384] bf16
    unsigned short* Ob = Qb + (size_t)P * 384;                     // [P][192] bf16
    float*          A32 = (float*)(Ob + (size_t)P * 192);          // [P][192] fp32

    dim3 blk(256);
    dim3 gpix(256);
    dim3 g360(512, 6);
    dim3 g180(512, 3);
    dim3 ga8(256, 6);
    dim3 ga16(256, 6);

    padzero<<<gpix, blk, 0, stream>>>(Qb, Ob);
    to_nhwc<<<gpix, blk, 0, stream>>>(x, A32);

    // ---- attn stage 0 ----
    mconv<180,360,0,192,0,0><<<g360, blk, 0, stream>>>(A32, a0_qkv_w, a0_qkv_b,
        a0_bn_g, a0_bn_b, a0_bn_m, a0_bn_v, nullptr, Qb);
    mattn<8> <<<ga8,  blk, 0, stream>>>(Qb, Ob, 0);
    mattn<16><<<ga16, blk, 0, stream>>>(Qb, Ob, 0);
    mconv<180,180,1,192,0,2><<<g180, blk, 0, stream>>>(Ob, a0_proj_w, a0_proj_b,
        nullptr, nullptr, nullptr, nullptr, A32, A32);

    // ---- mlp0 ----
    mconv<180,360,0,192,1,1><<<g360, blk, 0, stream>>>(A32, m0_fc1_w, m0_fc1_b,
        nullptr, nullptr, nullptr, nullptr, nullptr, Qb);
    mconv<360,180,1,384,1,2><<<g180, blk, 0, stream>>>(Qb, m0_fc2_w, m0_fc2_b,
        nullptr, nullptr, nullptr, nullptr, A32, A32);

    // ---- attn stage 1 ----
    mconv<180,360,0,192,0,0><<<g360, blk, 0, stream>>>(A32, a1_qkv_w, a1_qkv_b,
        a1_bn_g, a1_bn_b, a1_bn_m, a1_bn_v, nullptr, Qb);
    mattn<8> <<<ga8,  blk, 0, stream>>>(Qb, Ob, 4);
    mattn<16><<<ga16, blk, 0, stream>>>(Qb, Ob, 8);
    mconv<180,180,1,192,0,2><<<g180, blk, 0, stream>>>(Ob, a1_proj_w, a1_proj_b,
        nullptr, nullptr, nullptr, nullptr, A32, A32);

    // ---- mlp1 ----
    mconv<180,360,0,192,1,1><<<g360, blk, 0, stream>>>(A32, m1_fc1_w, m1_fc1_b,
        nullptr, nullptr, nullptr, nullptr, nullptr, Qb);
    mconv<360,180,1,384,1,2><<<g180, blk, 0, stream>>>(Qb, m1_fc2_w, m1_fc2_b,
        nullptr, nullptr, nullptr, nullptr, A32, A32);

    // ---- pixel mixer: Ob = bf16(x5) ----
    pixmixk<<<dim3(65536 * 45 / 256), blk, 0, stream>>>(A32, t2_bn_g, t2_bn_b,
        t2_bn_m, t2_bn_v, Ob);

    // ---- mlp2 (input/residual = Ob bf16) ----
    mconv<180,360,1,192,1,1><<<g360, blk, 0, stream>>>(Ob, m2_fc1_w, m2_fc1_b,
        nullptr, nullptr, nullptr, nullptr, nullptr, Qb);
    mconv<360,180,1,384,1,3><<<g180, blk, 0, stream>>>(Qb, m2_fc2_w, m2_fc2_b,
        nullptr, nullptr, nullptr, nullptr, Ob, A32);

    from_nhwc<<<gpix, blk, 0, stream>>>(A32, (float*)d_out);
}

// Round 4
// 786.943 us; speedup vs baseline: 2.5303x; 1.0785x over previous
//
#include <hip/hip_runtime.h>
#include <hip/hip_bf16.h>
#include <math.h>

#define P 65536

typedef float f32x4 __attribute__((ext_vector_type(4)));
typedef float f32x16 __attribute__((ext_vector_type(16)));
typedef short bf16x8 __attribute__((ext_vector_type(8)));
typedef unsigned short us8 __attribute__((ext_vector_type(8)));

__device__ __forceinline__ unsigned short f2b(float f) {
    __hip_bfloat16 h = __float2bfloat16(f);   // RNE, native cvt
    return __builtin_bit_cast(unsigned short, h);
}
__device__ __forceinline__ float b2f(unsigned short h) {
    return __builtin_bit_cast(float, (unsigned)h << 16);
}
__device__ __forceinline__ int shift_src(int g, int p) {
    int h = p >> 8, w = p & 255;
    if (g == 0) return (w < 255) ? p + 1 : -1;
    if (g == 1) return (w > 0) ? p - 1 : -1;
    if (g == 2) return (h < 255) ? p + 256 : -1;
    if (g == 3) return (h > 0) ? p - 256 : -1;
    return p;
}

// ---------------------------------------------------------------------------
// x [180][65536] fp32 CHW -> A32 [65536][192] fp32 NHWC (pads zeroed)
// ---------------------------------------------------------------------------
__global__ __launch_bounds__(256) void to_nhwc(const float* __restrict__ x,
                                               float* __restrict__ A32) {
    const int p = blockIdx.x * 256 + threadIdx.x;
    #pragma unroll
    for (int c4 = 0; c4 < 45; c4++) {
        float4 v;
        v.x = x[(size_t)(c4 * 4 + 0) * P + p];
        v.y = x[(size_t)(c4 * 4 + 1) * P + p];
        v.z = x[(size_t)(c4 * 4 + 2) * P + p];
        v.w = x[(size_t)(c4 * 4 + 3) * P + p];
        *(float4*)&A32[(size_t)p * 192 + c4 * 4] = v;
    }
    float4 z = make_float4(0, 0, 0, 0);
    *(float4*)&A32[(size_t)p * 192 + 180] = z;
    *(float4*)&A32[(size_t)p * 192 + 184] = z;
    *(float4*)&A32[(size_t)p * 192 + 188] = z;
}

// A32 [65536][192] NHWC -> d_out [180][65536] CHW
__global__ __launch_bounds__(256) void from_nhwc(const float* __restrict__ A32,
                                                 float* __restrict__ out) {
    const int p = blockIdx.x * 256 + threadIdx.x;
    #pragma unroll
    for (int c4 = 0; c4 < 45; c4++) {
        float4 v = *(const float4*)&A32[(size_t)p * 192 + c4 * 4];
        out[(size_t)(c4 * 4 + 0) * P + p] = v.x;
        out[(size_t)(c4 * 4 + 1) * P + p] = v.y;
        out[(size_t)(c4 * 4 + 2) * P + p] = v.z;
        out[(size_t)(c4 * 4 + 3) * P + p] = v.w;
    }
}

// zero pad columns of Qb (ch 360..383) and Ob (ch 180..191)
__global__ __launch_bounds__(256) void padzero(unsigned short* __restrict__ Qb,
                                               unsigned short* __restrict__ Ob) {
    const int p = blockIdx.x * 256 + threadIdx.x;
    us8 z = {0, 0, 0, 0, 0, 0, 0, 0};
    *(us8*)&Qb[(size_t)p * 384 + 360] = z;
    *(us8*)&Qb[(size_t)p * 384 + 368] = z;
    *(us8*)&Qb[(size_t)p * 384 + 376] = z;
    ushort4 z4 = {0, 0, 0, 0};
    *(ushort4*)&Ob[(size_t)p * 192 + 180] = z4;
    *(ushort4*)&Ob[(size_t)p * 192 + 184] = z4;
    *(ushort4*)&Ob[(size_t)p * 192 + 188] = z4;
}

// ---------------------------------------------------------------------------
// weight convert: W [OC][K] fp32 -> Wb [384][KP] bf16, zero-padded both dims
// ---------------------------------------------------------------------------
__global__ __launch_bounds__(256) void wcvt(const float* __restrict__ W,
                                            unsigned short* __restrict__ Wb,
                                            int OC, int K, int KP) {
    const int idx = blockIdx.x * 256 + threadIdx.x;   // over 384*KP
    const int oc = idx / KP, k = idx - oc * KP;
    unsigned short v = 0;
    if (oc < OC && k < K) v = f2b(W[(size_t)oc * K + k]);
    Wb[idx] = v;
}

// ---------------------------------------------------------------------------
// MFMA conv1x1 v2: C[pix][oc] = X[pix][k] . Wb^T[k][oc]
// Block: 256 thr = 4 waves (2x2), tile 128 pix x 128 oc, K-chunks of 64.
// Weights pre-converted bf16 [384][KP]. Shift granules are 4-wide where the
// group size (36) requires it (fixes boundary-straddle bug).
// EPI: 0 = BN affine -> bf16 Qb(384)   1 = bias+GELU -> bf16 Qb(384)
//      2 = bias + fp32 residual(A32) -> A32   3 = bias + bf16 residual(Ob) -> A32
// ---------------------------------------------------------------------------
template<int CIN, int COUT, int SRCB16, int SSTR, int SHIFT, int EPI>
__global__ __launch_bounds__(256, 4) void mconv2(
    const void* __restrict__ Xsrc, const unsigned short* __restrict__ Wb,
    const float* __restrict__ Bi,
    const float* __restrict__ bg, const float* __restrict__ bb,
    const float* __restrict__ bm, const float* __restrict__ bv,
    const void* __restrict__ Res, void* __restrict__ Out)
{
    constexpr int KP = (CIN == 180) ? 192 : 384;
    constexpr int NCH = KP / 64;
    constexpr int GS = CIN / 5;

    __shared__ __align__(16) unsigned short lx[128][72];
    __shared__ __align__(16) unsigned short lw[128][72];

    const int tid = threadIdx.x;
    const int lane = tid & 63, wid = tid >> 6;
    const int wm = wid >> 1, wn = wid & 1;
    const int pbase = blockIdx.x * 128, nbase = blockIdx.y * 128;

    f32x4 acc[4][4];
    #pragma unroll
    for (int a = 0; a < 4; a++)
        #pragma unroll
        for (int b = 0; b < 4; b++) acc[a][b] = (f32x4){0.f, 0.f, 0.f, 0.f};

    for (int ch = 0; ch < NCH; ++ch) {
        const int kc0 = ch * 64;
        if (ch) __syncthreads();
        // ---- stage W tile [128 oc][64 k] : 4 x us8 per thread ----
        #pragma unroll
        for (int i = 0; i < 4; i++) {
            int idx = tid + i * 256;
            int row = idx >> 3, c8 = (idx & 7) * 8;
            *(us8*)&lw[row][c8] = *(const us8*)&Wb[(size_t)(nbase + row) * KP + kc0 + c8];
        }
        // ---- stage X tile [128 pix][64 k] ----
        if constexpr (!SRCB16) {
            const float* X32 = (const float*)Xsrc;
            #pragma unroll
            for (int i = 0; i < 8; i++) {
                int idx = tid + i * 256;
                int row = idx >> 4, c4 = (idx & 15) * 4;
                int cc = kc0 + c4;
                int p = pbase + row;
                float4 xv = make_float4(0, 0, 0, 0);
                if constexpr (SHIFT) {
                    if (cc < CIN) {
                        int sp = shift_src(cc / GS, p);
                        if (sp >= 0) xv = *(const float4*)&X32[(size_t)sp * 192 + cc];
                    }
                } else {
                    xv = *(const float4*)&X32[(size_t)p * 192 + cc]; // pads are 0
                }
                ushort4 b4 = {f2b(xv.x), f2b(xv.y), f2b(xv.z), f2b(xv.w)};
                *(ushort4*)&lx[row][c4] = b4;
            }
        } else if constexpr (SHIFT && CIN == 180) {
            // 4-wide granules: 36 % 4 == 0 -> group uniform within granule
            const unsigned short* XB = (const unsigned short*)Xsrc;
            #pragma unroll
            for (int i = 0; i < 8; i++) {
                int idx = tid + i * 256;
                int row = idx >> 4, c4 = (idx & 15) * 4;
                int cc = kc0 + c4;
                int p = pbase + row;
                ushort4 hv = {0, 0, 0, 0};
                if (cc < CIN) {
                    int sp = shift_src(cc / GS, p);
                    if (sp >= 0) hv = *(const ushort4*)&XB[(size_t)sp * SSTR + cc];
                }
                *(ushort4*)&lx[row][c4] = hv;
            }
        } else {
            // us8 granules: CIN==360 shift has GS=72 (72%8==0, safe); non-shift direct
            const unsigned short* XB = (const unsigned short*)Xsrc;
            #pragma unroll
            for (int i = 0; i < 4; i++) {
                int idx = tid + i * 256;
                int row = idx >> 3, c8 = (idx & 7) * 8;
                int cc = kc0 + c8;
                int p = pbase + row;
                us8 hv = {0, 0, 0, 0, 0, 0, 0, 0};
                if constexpr (SHIFT) {
                    if (cc < CIN) {
                        int sp = shift_src(cc / GS, p);
                        if (sp >= 0) hv = *(const us8*)&XB[(size_t)sp * SSTR + cc];
                    }
                } else {
                    hv = *(const us8*)&XB[(size_t)p * SSTR + cc]; // pads are 0
                }
                *(us8*)&lx[row][c8] = hv;
            }
        }
        __syncthreads();
        // ---- compute: 2 k-steps of 32 ----
        #pragma unroll
        for (int ks = 0; ks < 2; ++ks) {
            const int ko = ks * 32 + (lane >> 4) * 8;
            bf16x8 av[4], bvv[4];
            #pragma unroll
            for (int mf = 0; mf < 4; mf++)
                av[mf] = *(const bf16x8*)&lx[wm * 64 + mf * 16 + (lane & 15)][ko];
            #pragma unroll
            for (int nf = 0; nf < 4; nf++)
                bvv[nf] = *(const bf16x8*)&lw[wn * 64 + nf * 16 + (lane & 15)][ko];
            #pragma unroll
            for (int mf = 0; mf < 4; mf++)
                #pragma unroll
                for (int nf = 0; nf < 4; nf++)
                    acc[mf][nf] = __builtin_amdgcn_mfma_f32_16x16x32_bf16(
                        av[mf], bvv[nf], acc[mf][nf], 0, 0, 0);
        }
    }

    // ---- epilogue ----
    #pragma unroll
    for (int nf = 0; nf < 4; ++nf) {
        const int oc = nbase + wn * 64 + nf * 16 + (lane & 15);
        if (oc >= COUT) continue;
        float sc = 1.f, sh;
        if constexpr (EPI == 0) {
            float inv = bg[oc] * rsqrtf(bv[oc] + 1e-5f);
            sc = inv;
            sh = bb[oc] + (Bi[oc] - bm[oc]) * inv;
        } else {
            sh = Bi[oc];
        }
        #pragma unroll
        for (int mf = 0; mf < 4; ++mf) {
            #pragma unroll
            for (int r = 0; r < 4; ++r) {
                const int pix = pbase + wm * 64 + mf * 16 + (lane >> 4) * 4 + r;
                float y = acc[mf][nf][r] * sc + sh;
                if constexpr (EPI == 1)
                    y = 0.5f * y * (1.f + erff(y * 0.70710678118654752f));
                if constexpr (EPI <= 1) {
                    ((unsigned short*)Out)[(size_t)pix * 384 + oc] = f2b(y);
                } else if constexpr (EPI == 2) {
                    y += ((const float*)Res)[(size_t)pix * 192 + oc];
                    ((float*)Out)[(size_t)pix * 192 + oc] = y;
                } else {
                    y += b2f(((const unsigned short*)Res)[(size_t)pix * 192 + oc]);
                    ((float*)Out)[(size_t)pix * 192 + oc] = y;
                }
            }
        }
    }
}

// ---------------------------------------------------------------------------
// MFMA window attention via symmetric-S trick (unchanged from round 3).
// ---------------------------------------------------------------------------
template<int WSZ>
__global__ __launch_bounds__(256) void mattn(const unsigned short* __restrict__ Qb,
                                             unsigned short* __restrict__ Ob, int sh)
{
    constexpr int TOK = WSZ * WSZ;
    constexpr int WPB = (WSZ == 8) ? 4 : 1;
    constexpr int NMI = TOK / 32;

    __shared__ __align__(16) unsigned short q_s[WPB][TOK][24];
    __shared__ __align__(16) unsigned short v_s[WPB][TOK][16];

    const int tid = threadIdx.x;
    const int lane = tid & 63, wid = tid >> 6;
    const int la = lane & 31, h = lane >> 5;
    const int head = blockIdx.y;
    const int qoff = ((WSZ == 8) ? 0 : 180) + head * 15;
    const int voff = qoff + 90;
    const int obase = ((WSZ == 8) ? 0 : 90) + head * 15;

    const int win = (WSZ == 8) ? (blockIdx.x * 4 + wid) : blockIdx.x;
    const int wy = win >> ((WSZ == 8) ? 5 : 4);
    const int wx = win & ((WSZ == 8) ? 31 : 15);

    {
        const int sw = (WSZ == 8) ? wid : 0;
        const int t = (WSZ == 8) ? (tid & 63) : tid;
        const int ty = t / WSZ, tx = t % WSZ;
        const int gh = (wy * WSZ + ty - sh) & 255;
        const int gw = (wx * WSZ + tx - sh) & 255;
        const unsigned short* src = Qb + (size_t)((gh << 8) | gw) * 384;
        #pragma unroll
        for (int c = 0; c < 15; c++) {
            q_s[sw][t][c] = src[qoff + c];
            v_s[sw][t][c] = src[voff + c];
        }
        q_s[sw][t][15] = 0;
        v_s[sw][t][15] = 0;
    }
    __syncthreads();

    const int mywin = (WSZ == 8) ? wid : 0;
    const unsigned short (*qs)[24] = q_s[mywin];
    const unsigned short (*vs)[16] = v_s[mywin];
    const int ni0 = (WSZ == 8) ? 0 : (wid * 2);
    const int ni1 = ni0 + 1;

    bf16x8 bfr0 = *(const bf16x8*)&qs[ni0 * 32 + la][h * 8];
    bf16x8 bfr1 = *(const bf16x8*)&qs[ni1 * 32 + la][h * 8];

    f32x16 O0, O1;
    #pragma unroll
    for (int r = 0; r < 16; r++) { O0[r] = 0.f; O1[r] = 0.f; }
    float m0 = -3.0e38f, m1 = -3.0e38f, l0 = 0.f, l1 = 0.f;

    unsigned short hw0[16], hw1[16];

    auto proc = [&](f32x16& S, float& m, float& l, f32x16& O, unsigned short* hw) {
        float vm = S[0];
        #pragma unroll
        for (int r = 1; r < 16; r++) vm = fmaxf(vm, S[r]);
        vm = fmaxf(vm, __shfl_xor(vm, 32));
        float nm = fmaxf(m, vm);
        float rs = __expf(m - nm);
        m = nm;
        l *= rs;
        #pragma unroll
        for (int r = 0; r < 16; r++) O[r] *= rs;
        float lacc = 0.f;
        #pragma unroll
        for (int r = 0; r < 16; r++) {
            unsigned short u = f2b(__expf(S[r] - nm));
            hw[r] = u;
            lacc += b2f(u);
        }
        l += lacc;
    };

    auto pack = [&](const unsigned short* hw, int sub) -> bf16x8 {
        unsigned A01 = (unsigned)hw[8 * sub + 0] | ((unsigned)hw[8 * sub + 1] << 16);
        unsigned A23 = (unsigned)hw[8 * sub + 2] | ((unsigned)hw[8 * sub + 3] << 16);
        unsigned B01 = (unsigned)hw[8 * sub + 4] | ((unsigned)hw[8 * sub + 5] << 16);
        unsigned B23 = (unsigned)hw[8 * sub + 6] | ((unsigned)hw[8 * sub + 7] << 16);
        unsigned x1 = (unsigned)__shfl_xor((int)(h ? A01 : B01), 32);
        unsigned x2 = (unsigned)__shfl_xor((int)(h ? A23 : B23), 32);
        union { unsigned u[4]; bf16x8 v; } pf;
        pf.u[0] = h ? x1 : A01;
        pf.u[1] = h ? x2 : A23;
        pf.u[2] = h ? B01 : x1;
        pf.u[3] = h ? B23 : x2;
        return pf.v;
    };

    for (int mi = 0; mi < NMI; ++mi) {
        bf16x8 af = *(const bf16x8*)&qs[mi * 32 + la][h * 8];
        f32x16 z;
        #pragma unroll
        for (int r = 0; r < 16; r++) z[r] = 0.f;
        f32x16 s0 = __builtin_amdgcn_mfma_f32_32x32x16_bf16(af, bfr0, z, 0, 0, 0);
        f32x16 s1 = __builtin_amdgcn_mfma_f32_32x32x16_bf16(af, bfr1, z, 0, 0, 0);

        proc(s0, m0, l0, O0, hw0);
        proc(s1, m1, l1, O1, hw1);

        #pragma unroll
        for (int sub = 0; sub < 2; ++sub) {
            union { unsigned short us[8]; bf16x8 v; } av;
            #pragma unroll
            for (int j = 0; j < 8; j++)
                av.us[j] = vs[mi * 32 + sub * 16 + h * 8 + j][la & 15];
            bf16x8 pf0 = pack(hw0, sub);
            bf16x8 pf1 = pack(hw1, sub);
            O0 = __builtin_amdgcn_mfma_f32_32x32x16_bf16(av.v, pf0, O0, 0, 0, 0);
            O1 = __builtin_amdgcn_mfma_f32_32x32x16_bf16(av.v, pf1, O1, 0, 0, 0);
        }
    }

    #pragma unroll
    for (int t = 0; t < 2; ++t) {
        const f32x16& O = t ? O1 : O0;
        float l = t ? l1 : l0;
        const int ni = t ? ni1 : ni0;
        float lt = l + __shfl_xor(l, 32);
        float inv = 1.f / lt;
        const int R = ni * 32 + la;
        const int ty = R / WSZ, tx = R % WSZ;
        const int gh = (wy * WSZ + ty - sh) & 255;
        const int gw = (wx * WSZ + tx - sh) & 255;
        unsigned short* dst = Ob + (size_t)((gh << 8) | gw) * 192 + obase;
        #pragma unroll
        for (int reg = 0; reg < 16; ++reg) {
            const int ch = (reg & 3) + 8 * (reg >> 2) + 4 * h;
            if (ch < 15) dst[ch] = f2b(O[reg] * inv);
        }
    }
}

// ---------------------------------------------------------------------------
// pixel mixer: Ob = bf16( x + BN(pm(x) - x) ), x = A32 (NHWC). Circular rolls.
// ---------------------------------------------------------------------------
__global__ __launch_bounds__(256) void pixmixk(const float* __restrict__ A32,
    const float* __restrict__ g, const float* __restrict__ b,
    const float* __restrict__ m, const float* __restrict__ v,
    unsigned short* __restrict__ Ob)
{
    const int idx = blockIdx.x * 256 + threadIdx.x; // 65536*45
    const int p = idx / 45;
    const int c0 = (idx - p * 45) * 4;
    const int h = p >> 8, w = p & 255;
    float4 x = *(const float4*)&A32[(size_t)p * 192 + c0];
    ushort4 o;
    #pragma unroll
    for (int j = 0; j < 4; j++) {
        int c = c0 + j;
        int gr = c - (c / 5) * 5;
        int sp;
        if (gr == 0)      sp = (h << 8) | ((w + 1) & 255);
        else if (gr == 1) sp = (h << 8) | ((w - 1) & 255);
        else if (gr == 2) sp = (((h + 1) & 255) << 8) | w;
        else if (gr == 3) sp = (((h - 1) & 255) << 8) | w;
        else              sp = p;
        float pm = A32[(size_t)sp * 192 + c];
        float xv = (j == 0) ? x.x : (j == 1) ? x.y : (j == 2) ? x.z : x.w;
        float inv = g[c] * rsqrtf(v[c] + 1e-5f);
        float y = xv + (pm - xv - m[c]) * inv + b[c];
        ((unsigned short*)&o)[j] = f2b(y);
    }
    *(ushort4*)&Ob[(size_t)p * 192 + c0] = o;
}

extern "C" void kernel_launch(void* const* d_in, const int* in_sizes, int n_in,
                              void* d_out, int out_size, void* d_ws, size_t ws_size,
                              hipStream_t stream)
{
    const float* x        = (const float*)d_in[0];
    const float* a0_qkv_w = (const float*)d_in[1];
    const float* a0_qkv_b = (const float*)d_in[2];
    const float* a0_bn_g  = (const float*)d_in[3];
    const float* a0_bn_b  = (const float*)d_in[4];
    const float* a0_bn_m  = (const float*)d_in[5];
    const float* a0_bn_v  = (const float*)d_in[6];
    const float* a0_proj_w= (const float*)d_in[7];
    const float* a0_proj_b= (const float*)d_in[8];
    const float* a1_qkv_w = (const float*)d_in[9];
    const float* a1_qkv_b = (const float*)d_in[10];
    const float* a1_bn_g  = (const float*)d_in[11];
    const float* a1_bn_b  = (const float*)d_in[12];
    const float* a1_bn_m  = (const float*)d_in[13];
    const float* a1_bn_v  = (const float*)d_in[14];
    const float* a1_proj_w= (const float*)d_in[15];
    const float* a1_proj_b= (const float*)d_in[16];
    const float* t2_bn_g  = (const float*)d_in[17];
    const float* t2_bn_b  = (const float*)d_in[18];
    const float* t2_bn_m  = (const float*)d_in[19];
    const float* t2_bn_v  = (const float*)d_in[20];
    const float* m0_fc1_w = (const float*)d_in[21];
    const float* m0_fc1_b = (const float*)d_in[22];
    const float* m0_fc2_w = (const float*)d_in[23];
    const float* m0_fc2_b = (const float*)d_in[24];
    const float* m1_fc1_w = (const float*)d_in[25];
    const float* m1_fc1_b = (const float*)d_in[26];
    const float* m1_fc2_w = (const float*)d_in[27];
    const float* m1_fc2_b = (const float*)d_in[28];
    const float* m2_fc1_w = (const float*)d_in[29];
    const float* m2_fc1_b = (const float*)d_in[30];
    const float* m2_fc2_w = (const float*)d_in[31];
    const float* m2_fc2_b = (const float*)d_in[32];

    unsigned short* Qb  = (unsigned short*)d_ws;                   // [P][384] bf16
    unsigned short* Ob  = Qb + (size_t)P * 384;                    // [P][192] bf16
    float*          A32 = (float*)(Ob + (size_t)P * 192);          // [P][192] fp32
    unsigned short* Wp  = (unsigned short*)(A32 + (size_t)P * 192);
    const size_t W192 = 384 * 192, W384 = (size_t)384 * 384;
    unsigned short* wb_qkv0 = Wp;
    unsigned short* wb_prj0 = wb_qkv0 + W192;
    unsigned short* wb_qkv1 = wb_prj0 + W192;
    unsigned short* wb_prj1 = wb_qkv1 + W192;
    unsigned short* wb_fc1_0 = wb_prj1 + W192;
    unsigned short* wb_fc1_1 = wb_fc1_0 + W192;
    unsigned short* wb_fc1_2 = wb_fc1_1 + W192;
    unsigned short* wb_fc2_0 = wb_fc1_2 + W192;
    unsigned short* wb_fc2_1 = wb_fc2_0 + W384;
    unsigned short* wb_fc2_2 = wb_fc2_1 + W384;

    dim3 blk(256);
    dim3 gpix(256);
    dim3 g360(512, 3);   // Cout 360 (padded 384): 3 tiles of 128
    dim3 g180(512, 2);   // Cout 180: 2 tiles of 128 (masked)
    dim3 ga8(256, 6);
    dim3 ga16(256, 6);

    // ---- one-time prep ----
    wcvt<<<288, blk, 0, stream>>>(a0_qkv_w, wb_qkv0, 360, 180, 192);
    wcvt<<<288, blk, 0, stream>>>(a0_proj_w, wb_prj0, 180, 180, 192);
    wcvt<<<288, blk, 0, stream>>>(a1_qkv_w, wb_qkv1, 360, 180, 192);
    wcvt<<<288, blk, 0, stream>>>(a1_proj_w, wb_prj1, 180, 180, 192);
    wcvt<<<288, blk, 0, stream>>>(m0_fc1_w, wb_fc1_0, 360, 180, 192);
    wcvt<<<288, blk, 0, stream>>>(m1_fc1_w, wb_fc1_1, 360, 180, 192);
    wcvt<<<288, blk, 0, stream>>>(m2_fc1_w, wb_fc1_2, 360, 180, 192);
    wcvt<<<576, blk, 0, stream>>>(m0_fc2_w, wb_fc2_0, 180, 360, 384);
    wcvt<<<576, blk, 0, stream>>>(m1_fc2_w, wb_fc2_1, 180, 360, 384);
    wcvt<<<576, blk, 0, stream>>>(m2_fc2_w, wb_fc2_2, 180, 360, 384);
    padzero<<<gpix, blk, 0, stream>>>(Qb, Ob);
    to_nhwc<<<gpix, blk, 0, stream>>>(x, A32);

    // ---- attn stage 0 ----
    mconv2<180,360,0,192,0,0><<<g360, blk, 0, stream>>>(A32, wb_qkv0, a0_qkv_b,
        a0_bn_g, a0_bn_b, a0_bn_m, a0_bn_v, nullptr, Qb);
    mattn<8> <<<ga8,  blk, 0, stream>>>(Qb, Ob, 0);
    mattn<16><<<ga16, blk, 0, stream>>>(Qb, Ob, 0);
    mconv2<180,180,1,192,0,2><<<g180, blk, 0, stream>>>(Ob, wb_prj0, a0_proj_b,
        nullptr, nullptr, nullptr, nullptr, A32, A32);

    // ---- mlp0 ----
    mconv2<180,360,0,192,1,1><<<g360, blk, 0, stream>>>(A32, wb_fc1_0, m0_fc1_b,
        nullptr, nullptr, nullptr, nullptr, nullptr, Qb);
    mconv2<360,180,1,384,1,2><<<g180, blk, 0, stream>>>(Qb, wb_fc2_0, m0_fc2_b,
        nullptr, nullptr, nullptr, nullptr, A32, A32);

    // ---- attn stage 1 ----
    mconv2<180,360,0,192,0,0><<<g360, blk, 0, stream>>>(A32, wb_qkv1, a1_qkv_b,
        a1_bn_g, a1_bn_b, a1_bn_m, a1_bn_v, nullptr, Qb);
    mattn<8> <<<ga8,  blk, 0, stream>>>(Qb, Ob, 4);
    mattn<16><<<ga16, blk, 0, stream>>>(Qb, Ob, 8);
    mconv2<180,180,1,192,0,2><<<g180, blk, 0, stream>>>(Ob, wb_prj1, a1_proj_b,
        nullptr, nullptr, nullptr, nullptr, A32, A32);

    // ---- mlp1 ----
    mconv2<180,360,0,192,1,1><<<g360, blk, 0, stream>>>(A32, wb_fc1_1, m1_fc1_b,
        nullptr, nullptr, nullptr, nullptr, nullptr, Qb);
    mconv2<360,180,1,384,1,2><<<g180, blk, 0, stream>>>(Qb, wb_fc2_1, m1_fc2_b,
        nullptr, nullptr, nullptr, nullptr, A32, A32);

    // ---- pixel mixer: Ob = bf16(x5) ----
    pixmixk<<<dim3(65536 * 45 / 256), blk, 0, stream>>>(A32, t2_bn_g, t2_bn_b,
        t2_bn_m, t2_bn_v, Ob);

    // ---- mlp2 (input/residual = Ob bf16; shift via 4-wide granules) ----
    mconv2<180,360,1,192,1,1><<<g360, blk, 0, stream>>>(Ob, wb_fc1_2, m2_fc1_b,
        nullptr, nullptr, nullptr, nullptr, nullptr, Qb);
    mconv2<360,180,1,384,1,3><<<g180, blk, 0, stream>>>(Qb, wb_fc2_2, m2_fc2_b,
        nullptr, nullptr, nullptr, nullptr, Ob, A32);

    from_nhwc<<<gpix, blk, 0, stream>>>(A32, (float*)d_out);
}

// Round 5
// 675.856 us; speedup vs baseline: 2.9462x; 1.1644x over previous
//
#include <hip/hip_runtime.h>
#include <hip/hip_bf16.h>
#include <math.h>

#define P 65536

typedef float f32x4 __attribute__((ext_vector_type(4)));
typedef float f32x16 __attribute__((ext_vector_type(16)));
typedef short bf16x8 __attribute__((ext_vector_type(8)));
typedef unsigned short us8 __attribute__((ext_vector_type(8)));

__device__ __forceinline__ unsigned short f2b(float f) {
    __hip_bfloat16 h = __float2bfloat16(f);   // RNE, native cvt
    return __builtin_bit_cast(unsigned short, h);
}
__device__ __forceinline__ float b2f(unsigned short h) {
    return __builtin_bit_cast(float, (unsigned)h << 16);
}
__device__ __forceinline__ int shift_src(int g, int p) {
    int h = p >> 8, w = p & 255;
    if (g == 0) return (w < 255) ? p + 1 : -1;
    if (g == 1) return (w > 0) ? p - 1 : -1;
    if (g == 2) return (h < 255) ? p + 256 : -1;
    if (g == 3) return (h > 0) ? p - 256 : -1;
    return p;
}

// ---------------------------------------------------------------------------
// x [180][65536] fp32 CHW -> A32 [65536][192] fp32 NHWC (pads zeroed)
// ---------------------------------------------------------------------------
__global__ __launch_bounds__(256) void to_nhwc(const float* __restrict__ x,
                                               float* __restrict__ A32) {
    const int p = blockIdx.x * 256 + threadIdx.x;
    #pragma unroll
    for (int c4 = 0; c4 < 45; c4++) {
        float4 v;
        v.x = x[(size_t)(c4 * 4 + 0) * P + p];
        v.y = x[(size_t)(c4 * 4 + 1) * P + p];
        v.z = x[(size_t)(c4 * 4 + 2) * P + p];
        v.w = x[(size_t)(c4 * 4 + 3) * P + p];
        *(float4*)&A32[(size_t)p * 192 + c4 * 4] = v;
    }
    float4 z = make_float4(0, 0, 0, 0);
    *(float4*)&A32[(size_t)p * 192 + 180] = z;
    *(float4*)&A32[(size_t)p * 192 + 184] = z;
    *(float4*)&A32[(size_t)p * 192 + 188] = z;
}

// A32 [65536][192] NHWC -> d_out [180][65536] CHW
__global__ __launch_bounds__(256) void from_nhwc(const float* __restrict__ A32,
                                                 float* __restrict__ out) {
    const int p = blockIdx.x * 256 + threadIdx.x;
    #pragma unroll
    for (int c4 = 0; c4 < 45; c4++) {
        float4 v = *(const float4*)&A32[(size_t)p * 192 + c4 * 4];
        out[(size_t)(c4 * 4 + 0) * P + p] = v.x;
        out[(size_t)(c4 * 4 + 1) * P + p] = v.y;
        out[(size_t)(c4 * 4 + 2) * P + p] = v.z;
        out[(size_t)(c4 * 4 + 3) * P + p] = v.w;
    }
}

// zero pad columns of Qb (ch 360..383) and Ob (ch 180..191)
__global__ __launch_bounds__(256) void padzero(unsigned short* __restrict__ Qb,
                                               unsigned short* __restrict__ Ob) {
    const int p = blockIdx.x * 256 + threadIdx.x;
    us8 z = {0, 0, 0, 0, 0, 0, 0, 0};
    *(us8*)&Qb[(size_t)p * 384 + 360] = z;
    *(us8*)&Qb[(size_t)p * 384 + 368] = z;
    *(us8*)&Qb[(size_t)p * 384 + 376] = z;
    ushort4 z4 = {0, 0, 0, 0};
    *(ushort4*)&Ob[(size_t)p * 192 + 180] = z4;
    *(ushort4*)&Ob[(size_t)p * 192 + 184] = z4;
    *(ushort4*)&Ob[(size_t)p * 192 + 188] = z4;
}

// ---------------------------------------------------------------------------
// weight convert: W [OC][K] fp32 -> Wb [384][KP] bf16, zero-padded both dims
// ---------------------------------------------------------------------------
__global__ __launch_bounds__(256) void wcvt(const float* __restrict__ W,
                                            unsigned short* __restrict__ Wb,
                                            int OC, int K, int KP) {
    const int idx = blockIdx.x * 256 + threadIdx.x;   // over 384*KP
    const int oc = idx / KP, k = idx - oc * KP;
    unsigned short v = 0;
    if (oc < OC && k < K) v = f2b(W[(size_t)oc * K + k]);
    Wb[idx] = v;
}

// ---------------------------------------------------------------------------
// mconvA: Cout=360 (padded 384), CIN=180 (KP=192). One block = 128 pix x ALL oc.
// 512 thr = 8 waves (2 pix-groups x 4 oc-groups of 48). X (full K) staged once
// in lx[128][196]; W streamed per 64-k chunk, 2 oc-halves of 192.
// SRCB16: input bf16[192] vs fp32 A32[192]. SHIFT: shift_plus (4-wide granules,
// group = c/36). EPI: 0 = BN -> Qb bf16(384)  1 = bias+GELU -> Qb bf16(384)
// ---------------------------------------------------------------------------
template<int SRCB16, int SHIFT, int EPI>
__global__ __launch_bounds__(512, 4) void mconvA(
    const void* __restrict__ Xsrc, const unsigned short* __restrict__ Wb,
    const float* __restrict__ Bi,
    const float* __restrict__ bg, const float* __restrict__ bb,
    const float* __restrict__ bm, const float* __restrict__ bv,
    unsigned short* __restrict__ Qb)
{
    __shared__ __align__(16) unsigned short lx[128][196];
    __shared__ __align__(16) unsigned short lw[192][76];

    const int tid = threadIdx.x;
    const int lane = tid & 63, wid = tid >> 6;
    const int wp = wid >> 2, wo = wid & 3;
    const int pbase = blockIdx.x * 128;

    // ---- stage X, full K=192, 4-wide granules (group size 36 % 4 == 0) ----
    #pragma unroll
    for (int i = 0; i < 12; i++) {
        int idx = tid + i * 512;
        int row = idx / 48, c4 = (idx % 48) * 4;
        int p = pbase + row;
        if constexpr (SRCB16) {
            const unsigned short* XB = (const unsigned short*)Xsrc;
            ushort4 hv = {0, 0, 0, 0};
            if constexpr (!SHIFT) {
                hv = *(const ushort4*)&XB[(size_t)p * 192 + c4];   // pads zero
            } else {
                if (c4 < 180) {
                    int sp = shift_src(c4 / 36, p);
                    if (sp >= 0) hv = *(const ushort4*)&XB[(size_t)sp * 192 + c4];
                }
            }
            *(ushort4*)&lx[row][c4] = hv;
        } else {
            const float* X32 = (const float*)Xsrc;
            float4 xv = make_float4(0, 0, 0, 0);
            if constexpr (!SHIFT) {
                xv = *(const float4*)&X32[(size_t)p * 192 + c4];   // pads zero
            } else {
                if (c4 < 180) {
                    int sp = shift_src(c4 / 36, p);
                    if (sp >= 0) xv = *(const float4*)&X32[(size_t)sp * 192 + c4];
                }
            }
            ushort4 b4 = {f2b(xv.x), f2b(xv.y), f2b(xv.z), f2b(xv.w)};
            *(ushort4*)&lx[row][c4] = b4;
        }
    }

    f32x4 acc[4][3];
    #pragma unroll
    for (int h = 0; h < 2; ++h) {
        #pragma unroll
        for (int a = 0; a < 4; a++)
            #pragma unroll
            for (int b = 0; b < 3; b++) acc[a][b] = (f32x4){0.f, 0.f, 0.f, 0.f};

        for (int ch = 0; ch < 3; ++ch) {
            __syncthreads();
            // stage W half-h chunk: [192 oc][64 k]
            #pragma unroll
            for (int i = 0; i < 3; i++) {
                int idx = tid + i * 512;
                int row = idx >> 3, c8 = (idx & 7) * 8;
                *(us8*)&lw[row][c8] =
                    *(const us8*)&Wb[(size_t)(h * 192 + row) * 192 + ch * 64 + c8];
            }
            __syncthreads();
            #pragma unroll
            for (int ks = 0; ks < 2; ++ks) {
                const int ko = ks * 32 + (lane >> 4) * 8;
                bf16x8 av[4], bvv[3];
                #pragma unroll
                for (int mf = 0; mf < 4; mf++)
                    av[mf] = *(const bf16x8*)&lx[wp * 64 + mf * 16 + (lane & 15)][ch * 64 + ko];
                #pragma unroll
                for (int nf = 0; nf < 3; nf++)
                    bvv[nf] = *(const bf16x8*)&lw[wo * 48 + nf * 16 + (lane & 15)][ko];
                #pragma unroll
                for (int mf = 0; mf < 4; mf++)
                    #pragma unroll
                    for (int nf = 0; nf < 3; nf++)
                        acc[mf][nf] = __builtin_amdgcn_mfma_f32_16x16x32_bf16(
                            av[mf], bvv[nf], acc[mf][nf], 0, 0, 0);
            }
        }
        // ---- epilogue for this oc-half ----
        #pragma unroll
        for (int nf = 0; nf < 3; ++nf) {
            const int oc = h * 192 + wo * 48 + nf * 16 + (lane & 15);
            if (oc >= 360) continue;
            float sc = 1.f, sh;
            if constexpr (EPI == 0) {
                float inv = bg[oc] * rsqrtf(bv[oc] + 1e-5f);
                sc = inv;
                sh = bb[oc] + (Bi[oc] - bm[oc]) * inv;
            } else {
                sh = Bi[oc];
            }
            #pragma unroll
            for (int mf = 0; mf < 4; ++mf) {
                #pragma unroll
                for (int r = 0; r < 4; ++r) {
                    const int pix = pbase + wp * 64 + mf * 16 + (lane >> 4) * 4 + r;
                    float y = acc[mf][nf][r] * sc + sh;
                    if constexpr (EPI == 1)
                        y = 0.5f * y * (1.f + erff(y * 0.70710678118654752f));
                    Qb[(size_t)pix * 384 + oc] = f2b(y);
                }
            }
        }
    }
}

// ---------------------------------------------------------------------------
// mconvB: Cout=180 (padded 192). One block = 128 pix x all 192 oc.
// 512 thr = 8 waves (2 pix x 4 oc-groups of 48). Per-chunk lx[128][76]+lw[192][76].
// Input bf16 stride KP. EPI: 2 = bias + fp32 residual(A32) -> A32 (in-place ok)
//                          3 = bias + bf16 residual(Ob) -> A32
// ---------------------------------------------------------------------------
template<int CIN, int SHIFT, int EPI>
__global__ __launch_bounds__(512, 4) void mconvB(
    const unsigned short* __restrict__ Xb, const unsigned short* __restrict__ Wb,
    const float* __restrict__ Bi,
    const void* __restrict__ Res, float* __restrict__ A32o)
{
    constexpr int KP = (CIN == 180) ? 192 : 384;
    constexpr int NCH = KP / 64;
    constexpr int GS = CIN / 5;   // 36 or 72

    __shared__ __align__(16) unsigned short lx[128][76];
    __shared__ __align__(16) unsigned short lw[192][76];

    const int tid = threadIdx.x;
    const int lane = tid & 63, wid = tid >> 6;
    const int wp = wid >> 2, wo = wid & 3;
    const int pbase = blockIdx.x * 128;

    f32x4 acc[4][3];
    #pragma unroll
    for (int a = 0; a < 4; a++)
        #pragma unroll
        for (int b = 0; b < 3; b++) acc[a][b] = (f32x4){0.f, 0.f, 0.f, 0.f};

    for (int ch = 0; ch < NCH; ++ch) {
        const int kc0 = ch * 64;
        if (ch) __syncthreads();
        // stage W chunk [192 oc][64 k]
        #pragma unroll
        for (int i = 0; i < 3; i++) {
            int idx = tid + i * 512;
            int row = idx >> 3, c8 = (idx & 7) * 8;
            *(us8*)&lw[row][c8] = *(const us8*)&Wb[(size_t)row * KP + kc0 + c8];
        }
        // stage X chunk [128 pix][64 k] (us8; GS=72 is us8-safe for SHIFT)
        #pragma unroll
        for (int i = 0; i < 2; i++) {
            int idx = tid + i * 512;
            int row = idx >> 3, c8 = (idx & 7) * 8;
            int cc = kc0 + c8;
            int p = pbase + row;
            us8 hv = {0, 0, 0, 0, 0, 0, 0, 0};
            if constexpr (SHIFT) {
                if (cc < CIN) {
                    int sp = shift_src(cc / GS, p);
                    if (sp >= 0) hv = *(const us8*)&Xb[(size_t)sp * KP + cc];
                }
            } else {
                hv = *(const us8*)&Xb[(size_t)p * KP + cc];   // pads zero
            }
            *(us8*)&lx[row][c8] = hv;
        }
        __syncthreads();
        #pragma unroll
        for (int ks = 0; ks < 2; ++ks) {
            const int ko = ks * 32 + (lane >> 4) * 8;
            bf16x8 av[4], bvv[3];
            #pragma unroll
            for (int mf = 0; mf < 4; mf++)
                av[mf] = *(const bf16x8*)&lx[wp * 64 + mf * 16 + (lane & 15)][ko];
            #pragma unroll
            for (int nf = 0; nf < 3; nf++)
                bvv[nf] = *(const bf16x8*)&lw[wo * 48 + nf * 16 + (lane & 15)][ko];
            #pragma unroll
            for (int mf = 0; mf < 4; mf++)
                #pragma unroll
                for (int nf = 0; nf < 3; nf++)
                    acc[mf][nf] = __builtin_amdgcn_mfma_f32_16x16x32_bf16(
                        av[mf], bvv[nf], acc[mf][nf], 0, 0, 0);
        }
    }

    #pragma unroll
    for (int nf = 0; nf < 3; ++nf) {
        const int oc = wo * 48 + nf * 16 + (lane & 15);
        if (oc >= 180) continue;
        const float sh = Bi[oc];
        #pragma unroll
        for (int mf = 0; mf < 4; ++mf) {
            #pragma unroll
            for (int r = 0; r < 4; ++r) {
                const int pix = pbase + wp * 64 + mf * 16 + (lane >> 4) * 4 + r;
                float y = acc[mf][nf][r] + sh;
                if constexpr (EPI == 2) {
                    y += ((const float*)Res)[(size_t)pix * 192 + oc];
                } else {
                    y += b2f(((const unsigned short*)Res)[(size_t)pix * 192 + oc]);
                }
                A32o[(size_t)pix * 192 + oc] = y;
            }
        }
    }
}

// ---------------------------------------------------------------------------
// MFMA window attention via symmetric-S trick (unchanged, verified).
// ---------------------------------------------------------------------------
template<int WSZ>
__global__ __launch_bounds__(256) void mattn(const unsigned short* __restrict__ Qb,
                                             unsigned short* __restrict__ Ob, int sh)
{
    constexpr int TOK = WSZ * WSZ;
    constexpr int WPB = (WSZ == 8) ? 4 : 1;
    constexpr int NMI = TOK / 32;

    __shared__ __align__(16) unsigned short q_s[WPB][TOK][24];
    __shared__ __align__(16) unsigned short v_s[WPB][TOK][16];

    const int tid = threadIdx.x;
    const int lane = tid & 63, wid = tid >> 6;
    const int la = lane & 31, h = lane >> 5;
    const int head = blockIdx.y;
    const int qoff = ((WSZ == 8) ? 0 : 180) + head * 15;
    const int voff = qoff + 90;
    const int obase = ((WSZ == 8) ? 0 : 90) + head * 15;

    const int win = (WSZ == 8) ? (blockIdx.x * 4 + wid) : blockIdx.x;
    const int wy = win >> ((WSZ == 8) ? 5 : 4);
    const int wx = win & ((WSZ == 8) ? 31 : 15);

    {
        const int sw = (WSZ == 8) ? wid : 0;
        const int t = (WSZ == 8) ? (tid & 63) : tid;
        const int ty = t / WSZ, tx = t % WSZ;
        const int gh = (wy * WSZ + ty - sh) & 255;
        const int gw = (wx * WSZ + tx - sh) & 255;
        const unsigned short* src = Qb + (size_t)((gh << 8) | gw) * 384;
        #pragma unroll
        for (int c = 0; c < 15; c++) {
            q_s[sw][t][c] = src[qoff + c];
            v_s[sw][t][c] = src[voff + c];
        }
        q_s[sw][t][15] = 0;
        v_s[sw][t][15] = 0;
    }
    __syncthreads();

    const int mywin = (WSZ == 8) ? wid : 0;
    const unsigned short (*qs)[24] = q_s[mywin];
    const unsigned short (*vs)[16] = v_s[mywin];
    const int ni0 = (WSZ == 8) ? 0 : (wid * 2);
    const int ni1 = ni0 + 1;

    bf16x8 bfr0 = *(const bf16x8*)&qs[ni0 * 32 + la][h * 8];
    bf16x8 bfr1 = *(const bf16x8*)&qs[ni1 * 32 + la][h * 8];

    f32x16 O0, O1;
    #pragma unroll
    for (int r = 0; r < 16; r++) { O0[r] = 0.f; O1[r] = 0.f; }
    float m0 = -3.0e38f, m1 = -3.0e38f, l0 = 0.f, l1 = 0.f;

    unsigned short hw0[16], hw1[16];

    auto proc = [&](f32x16& S, float& m, float& l, f32x16& O, unsigned short* hw) {
        float vm = S[0];
        #pragma unroll
        for (int r = 1; r < 16; r++) vm = fmaxf(vm, S[r]);
        vm = fmaxf(vm, __shfl_xor(vm, 32));
        float nm = fmaxf(m, vm);
        float rs = __expf(m - nm);
        m = nm;
        l *= rs;
        #pragma unroll
        for (int r = 0; r < 16; r++) O[r] *= rs;
        float lacc = 0.f;
        #pragma unroll
        for (int r = 0; r < 16; r++) {
            unsigned short u = f2b(__expf(S[r] - nm));
            hw[r] = u;
            lacc += b2f(u);
        }
        l += lacc;
    };

    auto pack = [&](const unsigned short* hw, int sub) -> bf16x8 {
        unsigned A01 = (unsigned)hw[8 * sub + 0] | ((unsigned)hw[8 * sub + 1] << 16);
        unsigned A23 = (unsigned)hw[8 * sub + 2] | ((unsigned)hw[8 * sub + 3] << 16);
        unsigned B01 = (unsigned)hw[8 * sub + 4] | ((unsigned)hw[8 * sub + 5] << 16);
        unsigned B23 = (unsigned)hw[8 * sub + 6] | ((unsigned)hw[8 * sub + 7] << 16);
        unsigned x1 = (unsigned)__shfl_xor((int)(h ? A01 : B01), 32);
        unsigned x2 = (unsigned)__shfl_xor((int)(h ? A23 : B23), 32);
        union { unsigned u[4]; bf16x8 v; } pf;
        pf.u[0] = h ? x1 : A01;
        pf.u[1] = h ? x2 : A23;
        pf.u[2] = h ? B01 : x1;
        pf.u[3] = h ? B23 : x2;
        return pf.v;
    };

    for (int mi = 0; mi < NMI; ++mi) {
        bf16x8 af = *(const bf16x8*)&qs[mi * 32 + la][h * 8];
        f32x16 z;
        #pragma unroll
        for (int r = 0; r < 16; r++) z[r] = 0.f;
        f32x16 s0 = __builtin_amdgcn_mfma_f32_32x32x16_bf16(af, bfr0, z, 0, 0, 0);
        f32x16 s1 = __builtin_amdgcn_mfma_f32_32x32x16_bf16(af, bfr1, z, 0, 0, 0);

        proc(s0, m0, l0, O0, hw0);
        proc(s1, m1, l1, O1, hw1);

        #pragma unroll
        for (int sub = 0; sub < 2; ++sub) {
            union { unsigned short us[8]; bf16x8 v; } av;
            #pragma unroll
            for (int j = 0; j < 8; j++)
                av.us[j] = vs[mi * 32 + sub * 16 + h * 8 + j][la & 15];
            bf16x8 pf0 = pack(hw0, sub);
            bf16x8 pf1 = pack(hw1, sub);
            O0 = __builtin_amdgcn_mfma_f32_32x32x16_bf16(av.v, pf0, O0, 0, 0, 0);
            O1 = __builtin_amdgcn_mfma_f32_32x32x16_bf16(av.v, pf1, O1, 0, 0, 0);
        }
    }

    #pragma unroll
    for (int t = 0; t < 2; ++t) {
        const f32x16& O = t ? O1 : O0;
        float l = t ? l1 : l0;
        const int ni = t ? ni1 : ni0;
        float lt = l + __shfl_xor(l, 32);
        float inv = 1.f / lt;
        const int R = ni * 32 + la;
        const int ty = R / WSZ, tx = R % WSZ;
        const int gh = (wy * WSZ + ty - sh) & 255;
        const int gw = (wx * WSZ + tx - sh) & 255;
        unsigned short* dst = Ob + (size_t)((gh << 8) | gw) * 192 + obase;
        #pragma unroll
        for (int reg = 0; reg < 16; ++reg) {
            const int ch = (reg & 3) + 8 * (reg >> 2) + 4 * h;
            if (ch < 15) dst[ch] = f2b(O[reg] * inv);
        }
    }
}

// ---------------------------------------------------------------------------
// pixel mixer: Ob = bf16( x + BN(pm(x) - x) ), x = A32 (NHWC). Circular rolls.
// ---------------------------------------------------------------------------
__global__ __launch_bounds__(256) void pixmixk(const float* __restrict__ A32,
    const float* __restrict__ g, const float* __restrict__ b,
    const float* __restrict__ m, const float* __restrict__ v,
    unsigned short* __restrict__ Ob)
{
    const int idx = blockIdx.x * 256 + threadIdx.x; // 65536*45
    const int p = idx / 45;
    const int c0 = (idx - p * 45) * 4;
    const int h = p >> 8, w = p & 255;
    float4 x = *(const float4*)&A32[(size_t)p * 192 + c0];
    ushort4 o;
    #pragma unroll
    for (int j = 0; j < 4; j++) {
        int c = c0 + j;
        int gr = c - (c / 5) * 5;
        int sp;
        if (gr == 0)      sp = (h << 8) | ((w + 1) & 255);
        else if (gr == 1) sp = (h << 8) | ((w - 1) & 255);
        else if (gr == 2) sp = (((h + 1) & 255) << 8) | w;
        else if (gr == 3) sp = (((h - 1) & 255) << 8) | w;
        else              sp = p;
        float pm = A32[(size_t)sp * 192 + c];
        float xv = (j == 0) ? x.x : (j == 1) ? x.y : (j == 2) ? x.z : x.w;
        float inv = g[c] * rsqrtf(v[c] + 1e-5f);
        float y = xv + (pm - xv - m[c]) * inv + b[c];
        ((unsigned short*)&o)[j] = f2b(y);
    }
    *(ushort4*)&Ob[(size_t)p * 192 + c0] = o;
}

extern "C" void kernel_launch(void* const* d_in, const int* in_sizes, int n_in,
                              void* d_out, int out_size, void* d_ws, size_t ws_size,
                              hipStream_t stream)
{
    const float* x        = (const float*)d_in[0];
    const float* a0_qkv_w = (const float*)d_in[1];
    const float* a0_qkv_b = (const float*)d_in[2];
    const float* a0_bn_g  = (const float*)d_in[3];
    const float* a0_bn_b  = (const float*)d_in[4];
    const float* a0_bn_m  = (const float*)d_in[5];
    const float* a0_bn_v  = (const float*)d_in[6];
    const float* a0_proj_w= (const float*)d_in[7];
    const float* a0_proj_b= (const float*)d_in[8];
    const float* a1_qkv_w = (const float*)d_in[9];
    const float* a1_qkv_b = (const float*)d_in[10];
    const float* a1_bn_g  = (const float*)d_in[11];
    const float* a1_bn_b  = (const float*)d_in[12];
    const float* a1_bn_m  = (const float*)d_in[13];
    const float* a1_bn_v  = (const float*)d_in[14];
    const float* a1_proj_w= (const float*)d_in[15];
    const float* a1_proj_b= (const float*)d_in[16];
    const float* t2_bn_g  = (const float*)d_in[17];
    const float* t2_bn_b  = (const float*)d_in[18];
    const float* t2_bn_m  = (const float*)d_in[19];
    const float* t2_bn_v  = (const float*)d_in[20];
    const float* m0_fc1_w = (const float*)d_in[21];
    const float* m0_fc1_b = (const float*)d_in[22];
    const float* m0_fc2_w = (const float*)d_in[23];
    const float* m0_fc2_b = (const float*)d_in[24];
    const float* m1_fc1_w = (const float*)d_in[25];
    const float* m1_fc1_b = (const float*)d_in[26];
    const float* m1_fc2_w = (const float*)d_in[27];
    const float* m1_fc2_b = (const float*)d_in[28];
    const float* m2_fc1_w = (const float*)d_in[29];
    const float* m2_fc1_b = (const float*)d_in[30];
    const float* m2_fc2_w = (const float*)d_in[31];
    const float* m2_fc2_b = (const float*)d_in[32];

    unsigned short* Qb  = (unsigned short*)d_ws;                   // [P][384] bf16
    unsigned short* Ob  = Qb + (size_t)P * 384;                    // [P][192] bf16
    float*          A32 = (float*)(Ob + (size_t)P * 192);          // [P][192] fp32
    unsigned short* Wp  = (unsigned short*)(A32 + (size_t)P * 192);
    const size_t W192 = 384 * 192, W384 = (size_t)384 * 384;
    unsigned short* wb_qkv0 = Wp;
    unsigned short* wb_prj0 = wb_qkv0 + W192;
    unsigned short* wb_qkv1 = wb_prj0 + W192;
    unsigned short* wb_prj1 = wb_qkv1 + W192;
    unsigned short* wb_fc1_0 = wb_prj1 + W192;
    unsigned short* wb_fc1_1 = wb_fc1_0 + W192;
    unsigned short* wb_fc1_2 = wb_fc1_1 + W192;
    unsigned short* wb_fc2_0 = wb_fc1_2 + W192;
    unsigned short* wb_fc2_1 = wb_fc2_0 + W384;
    unsigned short* wb_fc2_2 = wb_fc2_1 + W384;

    dim3 blk(256);
    dim3 blk512(512);
    dim3 gpix(256);
    dim3 gconv(512);
    dim3 ga8(256, 6);
    dim3 ga16(256, 6);

    // ---- one-time prep ----
    wcvt<<<288, blk, 0, stream>>>(a0_qkv_w, wb_qkv0, 360, 180, 192);
    wcvt<<<288, blk, 0, stream>>>(a0_proj_w, wb_prj0, 180, 180, 192);
    wcvt<<<288, blk, 0, stream>>>(a1_qkv_w, wb_qkv1, 360, 180, 192);
    wcvt<<<288, blk, 0, stream>>>(a1_proj_w, wb_prj1, 180, 180, 192);
    wcvt<<<288, blk, 0, stream>>>(m0_fc1_w, wb_fc1_0, 360, 180, 192);
    wcvt<<<288, blk, 0, stream>>>(m1_fc1_w, wb_fc1_1, 360, 180, 192);
    wcvt<<<288, blk, 0, stream>>>(m2_fc1_w, wb_fc1_2, 360, 180, 192);
    wcvt<<<576, blk, 0, stream>>>(m0_fc2_w, wb_fc2_0, 180, 360, 384);
    wcvt<<<576, blk, 0, stream>>>(m1_fc2_w, wb_fc2_1, 180, 360, 384);
    wcvt<<<576, blk, 0, stream>>>(m2_fc2_w, wb_fc2_2, 180, 360, 384);
    padzero<<<gpix, blk, 0, stream>>>(Qb, Ob);
    to_nhwc<<<gpix, blk, 0, stream>>>(x, A32);

    // ---- attn stage 0 ----
    mconvA<0,0,0><<<gconv, blk512, 0, stream>>>(A32, wb_qkv0, a0_qkv_b,
        a0_bn_g, a0_bn_b, a0_bn_m, a0_bn_v, Qb);
    mattn<8> <<<ga8,  blk, 0, stream>>>(Qb, Ob, 0);
    mattn<16><<<ga16, blk, 0, stream>>>(Qb, Ob, 0);
    mconvB<180,0,2><<<gconv, blk512, 0, stream>>>(Ob, wb_prj0, a0_proj_b, A32, A32);

    // ---- mlp0 ----
    mconvA<0,1,1><<<gconv, blk512, 0, stream>>>(A32, wb_fc1_0, m0_fc1_b,
        nullptr, nullptr, nullptr, nullptr, Qb);
    mconvB<360,1,2><<<gconv, blk512, 0, stream>>>(Qb, wb_fc2_0, m0_fc2_b, A32, A32);

    // ---- attn stage 1 ----
    mconvA<0,0,0><<<gconv, blk512, 0, stream>>>(A32, wb_qkv1, a1_qkv_b,
        a1_bn_g, a1_bn_b, a1_bn_m, a1_bn_v, Qb);
    mattn<8> <<<ga8,  blk, 0, stream>>>(Qb, Ob, 4);
    mattn<16><<<ga16, blk, 0, stream>>>(Qb, Ob, 8);
    mconvB<180,0,2><<<gconv, blk512, 0, stream>>>(Ob, wb_prj1, a1_proj_b, A32, A32);

    // ---- mlp1 ----
    mconvA<0,1,1><<<gconv, blk512, 0, stream>>>(A32, wb_fc1_1, m1_fc1_b,
        nullptr, nullptr, nullptr, nullptr, Qb);
    mconvB<360,1,2><<<gconv, blk512, 0, stream>>>(Qb, wb_fc2_1, m1_fc2_b, A32, A32);

    // ---- pixel mixer: Ob = bf16(x5) ----
    pixmixk<<<dim3(65536 * 45 / 256), blk, 0, stream>>>(A32, t2_bn_g, t2_bn_b,
        t2_bn_m, t2_bn_v, Ob);

    // ---- mlp2 (input Ob bf16 shifted; residual Ob bf16) ----
    mconvA<1,1,1><<<gconv, blk512, 0, stream>>>(Ob, wb_fc1_2, m2_fc1_b,
        nullptr, nullptr, nullptr, nullptr, Qb);
    mconvB<360,1,3><<<gconv, blk512, 0, stream>>>(Qb, wb_fc2_2, m2_fc2_b, Ob, A32);

    from_nhwc<<<gpix, blk, 0, stream>>>(A32, (float*)d_out);
}